// Round 1
// baseline (106909.460 us; speedup 1.0000x reference)
//
#include <hip/hip_runtime.h>
#include <cstddef>

// Basis-propagation reformulation:
//   s*(x) = K x + m (relaxation is linear);  E(x) = 0.5||x||^2 - vb.x + x~' H x~
//   H = sum_i S_i' (0.5 S_i - G_i),  S = [K | m] built by relaxing 785 columns
//   (784 pixel basis vectors + 1 affine column carrying the biases).

#define NB 785          // 784 basis + 1 affine column
#define DT 12800        // packed state dim: 6272 + 3136 + 3136 + 256
#define O1 0
#define D1 6272         // s1: 32 x 14 x 14
#define O2 6272
#define D2 3136         // s2: 64 x 7 x 7
#define O3 9408
#define D3 3136         // s3: 64 x 7 x 7
#define O4 12544
#define D4 256          // s4: 256
#define NITER 50

__global__ void k_fill0(float* p, int n) {
  for (int i = blockIdx.x * blockDim.x + threadIdx.x; i < n; i += gridDim.x * blockDim.x)
    p[i] = 0.f;
}

// w4t[k*256 + o] = w4[o*3136 + k]
__global__ void k_tr_w4(const float* __restrict__ w4, float* __restrict__ w4t) {
  int i = blockIdx.x * blockDim.x + threadIdx.x;
  if (i >= 256 * 3136) return;
  int o = i / 3136, k = i % 3136;
  w4t[k * 256 + o] = w4[i];
}

// u1 (= G1 input field): conv1 of basis vectors; affine column gets b1.
__global__ void k_u1(float* __restrict__ g, const float* __restrict__ w1,
                     const float* __restrict__ b1) {
  int i = blockIdx.x * blockDim.x + threadIdx.x;
  if (i >= NB * D1) return;
  int n = i / D1, r = i % D1;
  int c = r / 196, p = r % 196, oy = p / 14, ox = p % 14;
  float v;
  if (n == NB - 1) {
    v = b1[c];
  } else {
    int py = n / 28, px = n % 28;
    int ky = py - (2 * oy - 1), kx = px - (2 * ox - 1);
    v = (ky >= 0 && ky < 3 && kx >= 0 && kx < 3) ? w1[c * 9 + ky * 3 + kx] : 0.f;
  }
  g[(size_t)n * DT + O1 + r] = v;
}

// s1' = 0.5 s1 + 0.5 (u1 + conv2^T s2)
__global__ void k_s1(float* __restrict__ snxt, const float* __restrict__ scur,
                     const float* __restrict__ g, const float* __restrict__ w2) {
  int i = blockIdx.x * blockDim.x + threadIdx.x;
  if (i >= NB * D1) return;
  int n = i / D1, r = i % D1;
  int c = r / 196, p = r % 196, y = p / 14, x = p % 14;
  float acc = g[(size_t)n * DT + O1 + r];   // u1 (constant input term)
  const float* s2 = scur + (size_t)n * DT + O2;
  for (int ky = 0; ky < 3; ++ky) {
    int ty = y + 1 - ky;
    if (ty & 1) continue;              // stride-2 adjoint: need even
    int oy = ty >> 1;
    if (oy < 0 || oy >= 7) continue;
    for (int kx = 0; kx < 3; ++kx) {
      int tx = x + 1 - kx;
      if (tx & 1) continue;
      int ox = tx >> 1;
      if (ox < 0 || ox >= 7) continue;
      const float* wp = w2 + c * 9 + ky * 3 + kx;  // w2[co][c][ky][kx], co stride 288
      const float* sp = s2 + oy * 7 + ox;          // s2[co], co stride 49
#pragma unroll 8
      for (int co = 0; co < 64; ++co) acc += wp[co * 288] * sp[co * 49];
    }
  }
  snxt[(size_t)n * DT + O1 + r] = 0.5f * scur[(size_t)n * DT + O1 + r] + 0.5f * acc;
}

// POST=0: s2' = 0.5 s2 + 0.5 (conv2(s1)+b2_aff + conv3^T s3)  -> dst=snxt
// POST=1: P2  = 0.5 s2 - (conv2(s1)+b2_aff)                   -> dst=g
template <int POST>
__global__ void k_s2(float* __restrict__ dst, const float* __restrict__ scur,
                     const float* __restrict__ w2, const float* __restrict__ w3,
                     const float* __restrict__ b2) {
  int i = blockIdx.x * blockDim.x + threadIdx.x;
  if (i >= NB * D2) return;
  int n = i / D2, r = i % D2;
  int c = r / 49, p = r % 49, y = p / 7, x = p % 7;
  float acc = (n == NB - 1) ? b2[c] : 0.f;
  // conv2 forward on s1 (stride 2, pad 1)
  const float* s1 = scur + (size_t)n * DT + O1;
  for (int ky = 0; ky < 3; ++ky) {
    int iy = 2 * y - 1 + ky;
    if (iy < 0 || iy >= 14) continue;
    for (int kx = 0; kx < 3; ++kx) {
      int ix = 2 * x - 1 + kx;
      if (ix < 0 || ix >= 14) continue;
      const float* wp = w2 + c * 288 + ky * 3 + kx;  // w2[c][ci][ky][kx], ci stride 9
      const float* sp = s1 + iy * 14 + ix;           // ci stride 196
#pragma unroll 8
      for (int ci = 0; ci < 32; ++ci) acc += wp[ci * 9] * sp[ci * 196];
    }
  }
  if (!POST) {
    // conv3^T on s3 (stride 1, pad 1)
    const float* s3 = scur + (size_t)n * DT + O3;
    for (int ky = 0; ky < 3; ++ky) {
      int ty = y + 1 - ky;
      if (ty < 0 || ty >= 7) continue;
      for (int kx = 0; kx < 3; ++kx) {
        int tx = x + 1 - kx;
        if (tx < 0 || tx >= 7) continue;
        const float* wp = w3 + c * 9 + ky * 3 + kx;  // w3[co][c][ky][kx], co stride 576
        const float* sp = s3 + ty * 7 + tx;          // co stride 49
#pragma unroll 8
        for (int co = 0; co < 64; ++co) acc += wp[co * 576] * sp[co * 49];
      }
    }
  }
  float prev = scur[(size_t)n * DT + O2 + r];
  dst[(size_t)n * DT + O2 + r] = POST ? (0.5f * prev - acc) : (0.5f * prev + 0.5f * acc);
}

// POST=0: s3' = 0.5 s3 + 0.5 (conv3(s2)+b3_aff + W4^T s4)   (W4^T s4 precomputed in t4)
// POST=1: P3  = 0.5 s3 - (conv3(s2)+b3_aff)
template <int POST>
__global__ void k_s3(float* __restrict__ dst, const float* __restrict__ scur,
                     const float* __restrict__ t4, const float* __restrict__ w3,
                     const float* __restrict__ b3) {
  int i = blockIdx.x * blockDim.x + threadIdx.x;
  if (i >= NB * D3) return;
  int n = i / D3, r = i % D3;
  int c = r / 49, p = r % 49, y = p / 7, x = p % 7;
  float acc = (n == NB - 1) ? b3[c] : 0.f;
  if (!POST) acc += t4[(size_t)n * 3136 + r];
  // conv3 forward on s2 (stride 1, pad 1)
  const float* s2 = scur + (size_t)n * DT + O2;
  for (int ky = 0; ky < 3; ++ky) {
    int iy = y - 1 + ky;
    if (iy < 0 || iy >= 7) continue;
    for (int kx = 0; kx < 3; ++kx) {
      int ix = x - 1 + kx;
      if (ix < 0 || ix >= 7) continue;
      const float* wp = w3 + c * 576 + ky * 3 + kx;  // w3[c][ci][ky][kx], ci stride 9
      const float* sp = s2 + iy * 7 + ix;            // ci stride 49
#pragma unroll 8
      for (int ci = 0; ci < 64; ++ci) acc += wp[ci * 9] * sp[ci * 49];
    }
  }
  float prev = scur[(size_t)n * DT + O3 + r];
  dst[(size_t)n * DT + O3 + r] = POST ? (0.5f * prev - acc) : (0.5f * prev + 0.5f * acc);
}

// P1 = 0.5 s1_final - u1   (in place on g slot O1)
__global__ void k_p1(float* __restrict__ g, const float* __restrict__ scur) {
  int i = blockIdx.x * blockDim.x + threadIdx.x;
  if (i >= NB * D1) return;
  int n = i / D1, r = i % D1;
  size_t idx = (size_t)n * DT + O1 + r;
  g[idx] = 0.5f * scur[idx] - g[idx];
}

// Generic tiled fp32 GEMM, "NT" layout: C[m,n] = a0*P0[m,n] + aacc*(sum_k A[m,k]*B[n,k] + bias)
// bias = biasN[n] applied (inside aacc) when biasN && (!bias_last_only || m==M-1).
// aug_a: logical A[m,K-1] == 1.0 (A physically has K-1 columns) — for the x~=[x;1] GEMM.
#define TS 16
__global__ void gemm_nt(float* __restrict__ C, int ldc, const float* __restrict__ A, int lda,
                        const float* __restrict__ B, int ldb, int M, int N, int K,
                        const float* __restrict__ P0, int ldp, float a0, float aacc,
                        const float* __restrict__ biasN, int bias_last_only, int aug_a) {
  __shared__ float As[TS][TS + 1], Bs[TS][TS + 1];
  int tx = threadIdx.x, ty = threadIdx.y;
  int m0 = blockIdx.y * TS, n0 = blockIdx.x * TS;
  int m = m0 + ty, n = n0 + tx;
  float acc = 0.f;
  for (int k0 = 0; k0 < K; k0 += TS) {
    int ka = k0 + tx;
    float av = 0.f;
    if (m < M && ka < K) {
      if (aug_a && ka == K - 1) av = 1.f;
      else av = A[(size_t)m * lda + ka];
    }
    As[ty][tx] = av;
    int nb = n0 + ty;
    float bv = 0.f;
    if (nb < N && ka < K) bv = B[(size_t)nb * ldb + ka];
    Bs[ty][tx] = bv;
    __syncthreads();
#pragma unroll
    for (int t = 0; t < TS; ++t) acc += As[ty][t] * Bs[tx][t];
    __syncthreads();
  }
  if (m < M && n < N) {
    if (biasN && (!bias_last_only || m == M - 1)) acc += biasN[n];
    float v = aacc * acc;
    if (P0) v += a0 * P0[(size_t)m * ldp + n];
    C[(size_t)m * ldc + n] = v;
  }
}

// out[i] = 0.5||x_i||^2 - vb.x_i + sum_{j<784} x_ij Y[i,j] + Y[i,784]
__global__ void k_out(float* __restrict__ out, const float* __restrict__ x,
                      const float* __restrict__ vb, const float* __restrict__ Y, int Bn) {
  int wave = threadIdx.x >> 6, lane = threadIdx.x & 63;
  int i = blockIdx.x * 4 + wave;
  if (i >= Bn) return;
  const float* xi = x + (size_t)i * 784;
  const float* yi = Y + (size_t)i * NB;
  float s = 0.f;
  for (int j = lane; j < 784; j += 64) {
    float xv = xi[j];
    s += xv * (0.5f * xv - vb[j] + yi[j]);
  }
  for (int off = 32; off; off >>= 1) s += __shfl_down(s, off);
  if (lane == 0) out[i] = s + yi[784];
}

extern "C" void kernel_launch(void* const* d_in, const int* in_sizes, int n_in, void* d_out,
                              int out_size, void* d_ws, size_t ws_size, hipStream_t stream) {
  const float* x  = (const float*)d_in[0];
  const float* vb = (const float*)d_in[1];
  const float* w1 = (const float*)d_in[2];
  const float* b1 = (const float*)d_in[3];
  const float* w2 = (const float*)d_in[4];
  const float* b2 = (const float*)d_in[5];
  const float* w3 = (const float*)d_in[6];
  const float* b3 = (const float*)d_in[7];
  const float* w4 = (const float*)d_in[8];
  const float* b4 = (const float*)d_in[9];
  int Bn = in_sizes[0] / 784;
  float* out = (float*)d_out;

  float* ws  = (float*)d_ws;
  float* sA  = ws;                          // NB*DT
  float* sB  = sA + (size_t)NB * DT;        // NB*DT
  float* g   = sB + (size_t)NB * DT;        // NB*DT   (u1 -> later P blocks)
  float* t4  = g + (size_t)NB * DT;         // NB*3136 (W4^T s4 scratch)
  float* w4t = t4 + (size_t)NB * 3136;      // 3136*256
  float* Ht  = w4t + (size_t)3136 * 256;    // NB*NB   (Ht[k,j] = H[j,k])
  float* Yb  = Ht + (size_t)NB * NB;        // Bn*NB

  const int TB = 256;
  // init
  k_fill0<<<2048, TB, 0, stream>>>(sA, NB * DT);
  k_tr_w4<<<(256 * 3136 + TB - 1) / TB, TB, 0, stream>>>(w4, w4t);
  k_u1<<<(NB * D1 + TB - 1) / TB, TB, 0, stream>>>(g, w1, b1);

  float* cur = sA;
  float* nxt = sB;
  dim3 tdim(TS, TS);
  for (int t = 0; t < NITER; ++t) {
    // t4[n,r] = sum_o s4[n,o] * w4t[r,o]   (M=NB, N=3136, K=256)
    gemm_nt<<<dim3(3136 / TS, (NB + TS - 1) / TS), tdim, 0, stream>>>(
        t4, 3136, cur + O4, DT, w4t, 256, NB, 3136, 256, nullptr, 0, 0.f, 1.f, nullptr, 0, 0);
    k_s1<<<(NB * D1 + TB - 1) / TB, TB, 0, stream>>>(nxt, cur, g, w2);
    k_s2<0><<<(NB * D2 + TB - 1) / TB, TB, 0, stream>>>(nxt, cur, w2, w3, b2);
    k_s3<0><<<(NB * D3 + TB - 1) / TB, TB, 0, stream>>>(nxt, cur, t4, w3, b3);
    // s4' = 0.5 s4 + 0.5 (W4 s3 + b4_aff)   (M=NB, N=256, K=3136)
    gemm_nt<<<dim3(256 / TS, (NB + TS - 1) / TS), tdim, 0, stream>>>(
        nxt + O4, DT, cur + O3, DT, w4, 3136, NB, 256, 3136, cur + O4, DT, 0.5f, 0.5f, b4, 1, 0);
    float* tmp = cur; cur = nxt; nxt = tmp;
  }

  // post: P = 0.5*S - G (into g)
  k_p1<<<(NB * D1 + TB - 1) / TB, TB, 0, stream>>>(g, cur);
  k_s2<1><<<(NB * D2 + TB - 1) / TB, TB, 0, stream>>>(g, cur, w2, w3, b2);
  k_s3<1><<<(NB * D3 + TB - 1) / TB, TB, 0, stream>>>(g, cur, nullptr, w3, b3);
  gemm_nt<<<dim3(256 / TS, (NB + TS - 1) / TS), tdim, 0, stream>>>(
      g + O4, DT, cur + O3, DT, w4, 3136, NB, 256, 3136, cur + O4, DT, 0.5f, -1.f, b4, 1, 0);

  // Ht[k,j] = sum_d P[k,d] * S[j,d]  (M=NB rows of g, N=NB rows of cur, K=DT)
  gemm_nt<<<dim3((NB + TS - 1) / TS, (NB + TS - 1) / TS), tdim, 0, stream>>>(
      Ht, NB, g, DT, cur, DT, NB, NB, DT, nullptr, 0, 0.f, 1.f, nullptr, 0, 0);

  // Y[i,k] = sum_j x~[i,j] * Ht[k,j]  (M=Bn, N=NB, K=NB, augmented A)
  gemm_nt<<<dim3((NB + TS - 1) / TS, (Bn + TS - 1) / TS), tdim, 0, stream>>>(
      Yb, NB, x, 784, Ht, NB, Bn, NB, NB, nullptr, 0, 0.f, 1.f, nullptr, 0, 1);

  // out
  k_out<<<(Bn + 3) / 4, TB, 0, stream>>>(out, x, vb, Yb, Bn);
}

// Round 2
// 13326.973 us; speedup vs baseline: 8.0220x; 8.0220x over previous
//
#include <hip/hip_runtime.h>
#include <cstddef>

// Basis-propagation reformulation, n-minor layout:
//   state S[d][n], d in [0,12800), n in [0,788): 785 used (784 pixel basis + 1 affine col), 3 zero pad.
//   Every op is a GEMM over n. E(x) = 0.5||x||^2 - vb.x + x~' H x~,  H = P' S, P = 0.5 S - G.

#define NB 785
#define NBp 788          // padded columns (mult of 4); pad cols stay exactly 0
#define DT 12800
#define O1 0
#define D1 6272          // s1: 32 x 14 x 14
#define O2 6272
#define D2 3136          // s2: 64 x 7 x 7
#define O3 9408
#define D3 3136          // s3: 64 x 7 x 7
#define O4 12544
#define D4 256
#define NITER 50

__device__ __forceinline__ int imin(int a, int b) { return a < b ? a : b; }

#define FMA16(AP, BP)                                                     \
  {                                                                       \
    float4 a_ = *(const float4*)(AP);                                     \
    float4 b_ = *(const float4*)(BP);                                     \
    acc[0][0] += a_.x * b_.x; acc[0][1] += a_.x * b_.y;                   \
    acc[0][2] += a_.x * b_.z; acc[0][3] += a_.x * b_.w;                   \
    acc[1][0] += a_.y * b_.x; acc[1][1] += a_.y * b_.y;                   \
    acc[1][2] += a_.y * b_.z; acc[1][3] += a_.y * b_.w;                   \
    acc[2][0] += a_.z * b_.x; acc[2][1] += a_.z * b_.y;                   \
    acc[2][2] += a_.z * b_.z; acc[2][3] += a_.z * b_.w;                   \
    acc[3][0] += a_.w * b_.x; acc[3][1] += a_.w * b_.y;                   \
    acc[3][2] += a_.w * b_.z; acc[3][3] += a_.w * b_.w;                   \
  }

__global__ void k_fill0(float* p, size_t n) {
  for (size_t i = blockIdx.x * (size_t)blockDim.x + threadIdx.x; i < n;
       i += (size_t)gridDim.x * blockDim.x)
    p[i] = 0.f;
}

// w2f[t][ci][co], w2b[t][co][ci]  from w2[co][ci][t]
__global__ void k_prep_w2(const float* __restrict__ w2, float* __restrict__ w2f,
                          float* __restrict__ w2b) {
  int idx = blockIdx.x * blockDim.x + threadIdx.x;
  if (idx >= 9 * 64 * 32) return;
  int t = idx / 2048, rem = idx % 2048, co = rem / 32, ci = rem % 32;
  float v = w2[co * 288 + ci * 9 + t];
  w2f[(t * 32 + ci) * 64 + co] = v;
  w2b[(t * 64 + co) * 32 + ci] = v;
}

// w3f[t][ci][co], w3b[t][co][ci]  from w3[co][ci][t]
__global__ void k_prep_w3(const float* __restrict__ w3, float* __restrict__ w3f,
                          float* __restrict__ w3b) {
  int idx = blockIdx.x * blockDim.x + threadIdx.x;
  if (idx >= 9 * 64 * 64) return;
  int t = idx / 4096, rem = idx % 4096, co = rem / 64, ci = rem % 64;
  float v = w3[co * 576 + ci * 9 + t];
  w3f[(t * 64 + ci) * 64 + co] = v;
  w3b[(t * 64 + co) * 64 + ci] = v;
}

// u1[d][n]: conv1 applied to basis vector n (affine col n==784 gets b1; pads 0)
__global__ void k_u1n(float* __restrict__ g, const float* __restrict__ w1,
                      const float* __restrict__ b1) {
  size_t idx = blockIdx.x * (size_t)blockDim.x + threadIdx.x;
  if (idx >= (size_t)D1 * NBp) return;
  int d = (int)(idx / NBp), n = (int)(idx % NBp);
  int c = d / 196, q = d % 196, oy = q / 14, ox = q % 14;
  float v = 0.f;
  if (n < 784) {
    int py = n / 28, px = n % 28;
    int ky = py - (2 * oy - 1), kx = px - (2 * ox - 1);
    if (ky >= 0 && ky < 3 && kx >= 0 && kx < 3) v = w1[c * 9 + ky * 3 + kx];
  } else if (n == 784) {
    v = b1[c];
  }
  g[idx] = v;
}

// P1 = 0.5*s1_final - u1 (in place on g's s1 region)
__global__ void k_p1n(float* __restrict__ g, const float* __restrict__ cur) {
  size_t idx = blockIdx.x * (size_t)blockDim.x + threadIdx.x;
  if (idx >= (size_t)D1 * NBp) return;
  g[idx] = 0.5f * cur[idx] - g[idx];
}

// s1' = 0.5 s1 + 0.5 (u1 + conv2^T s2).  Tile 32c x 128n, micro 4x4.
__global__ __launch_bounds__(256) void k_s1n(float* __restrict__ nxt,
                                             const float* __restrict__ cur,
                                             const float* __restrict__ g,
                                             const float* __restrict__ w2b) {
  __shared__ float As[64][32];
  __shared__ float Bs[64][128];
  const int tid = threadIdx.x;
  const int n4 = (tid & 31) * 4, c4 = (tid >> 5) * 4;
  const int n0 = blockIdx.x * 128;
  const int q = blockIdx.y;
  const int y = q / 14, x = q % 14;
  float acc[4][4] = {};
  for (int ky = 0; ky < 3; ++ky) {
    int ty_ = y + 1 - ky;
    if (ty_ & 1) continue;
    int oy = ty_ >> 1;
    if (oy < 0 || oy >= 7) continue;
    for (int kx = 0; kx < 3; ++kx) {
      int tx_ = x + 1 - kx;
      if (tx_ & 1) continue;
      int ox = tx_ >> 1;
      if (ox < 0 || ox >= 7) continue;
      int pin = oy * 7 + ox, t = ky * 3 + kx;
      __syncthreads();
      {  // As = w2b[t] : 64x32 contiguous
        const float* src = w2b + t * 2048;
        float* dl = &As[0][0];
#pragma unroll
        for (int r = 0; r < 2; ++r) {
          int f = r * 256 + tid;
          *(float4*)&dl[f * 4] = *(const float4*)&src[f * 4];
        }
      }
#pragma unroll
      for (int r = 0; r < 8; ++r) {  // Bs: 64 rows (co) x 128 n
        int f = r * 256 + tid;
        int row = f >> 5, col = (f & 31) * 4;
        float4 v = {0.f, 0.f, 0.f, 0.f};
        int n = n0 + col;
        if (n + 4 <= NBp)
          v = *(const float4*)&cur[(size_t)(O2 + row * 49 + pin) * NBp + n];
        *(float4*)&Bs[row][col] = v;
      }
      __syncthreads();
#pragma unroll 16
      for (int k = 0; k < 64; ++k) FMA16(&As[k][c4], &Bs[k][n4]);
    }
  }
  int n = n0 + n4;
  if (n + 4 <= NBp) {
#pragma unroll
    for (int i = 0; i < 4; ++i) {
      size_t off = (size_t)(O1 + (c4 + i) * 196 + q) * NBp + n;
      float4 pv = *(const float4*)&cur[off];
      float4 gv = *(const float4*)&g[off];
      float4 o;
      o.x = 0.5f * pv.x + 0.5f * (gv.x + acc[i][0]);
      o.y = 0.5f * pv.y + 0.5f * (gv.y + acc[i][1]);
      o.z = 0.5f * pv.z + 0.5f * (gv.z + acc[i][2]);
      o.w = 0.5f * pv.w + 0.5f * (gv.w + acc[i][3]);
      *(float4*)&nxt[off] = o;
    }
  }
}

// POST=0: s2' = 0.5 s2 + 0.5 (conv2(s1)+b2_aff + conv3^T s3)
// POST=1: P2  = 0.5 s2 - (conv2(s1)+b2_aff)
template <int POST>
__global__ __launch_bounds__(256) void k_s2n(float* __restrict__ dst,
                                             const float* __restrict__ cur,
                                             const float* __restrict__ w2f,
                                             const float* __restrict__ w3b,
                                             const float* __restrict__ b2) {
  __shared__ float As[64][64];
  __shared__ float Bs[64][64];
  const int tid = threadIdx.x;
  const int n4 = (tid & 15) * 4, c4 = (tid >> 4) * 4;
  const int n0 = blockIdx.x * 64;
  const int p = blockIdx.y;
  const int y = p / 7, xx = p % 7;
  float acc[4][4] = {};
  // phase 1: conv2 forward on s1 (CIN=32)
  for (int ky = 0; ky < 3; ++ky) {
    int iy = 2 * y - 1 + ky;
    if (iy < 0 || iy >= 14) continue;
    for (int kx = 0; kx < 3; ++kx) {
      int ix = 2 * xx - 1 + kx;
      if (ix < 0 || ix >= 14) continue;
      int pin = iy * 14 + ix, t = ky * 3 + kx;
      __syncthreads();
      {
        const float* src = w2f + t * 2048;  // 32x64
        float* dl = &As[0][0];
#pragma unroll
        for (int r = 0; r < 2; ++r) {
          int f = r * 256 + tid;
          *(float4*)&dl[f * 4] = *(const float4*)&src[f * 4];
        }
      }
#pragma unroll
      for (int r = 0; r < 2; ++r) {  // 32 rows x 64
        int f = r * 256 + tid;
        int row = f >> 4, col = (f & 15) * 4;
        float4 v = {0.f, 0.f, 0.f, 0.f};
        int n = n0 + col;
        if (n + 4 <= NBp)
          v = *(const float4*)&cur[(size_t)(O1 + row * 196 + pin) * NBp + n];
        *(float4*)&Bs[row][col] = v;
      }
      __syncthreads();
#pragma unroll 16
      for (int k = 0; k < 32; ++k) FMA16(&As[k][c4], &Bs[k][n4]);
    }
  }
  if (!POST) {  // phase 2: conv3^T on s3 (CIN=64)
    for (int ky = 0; ky < 3; ++ky) {
      int ty_ = y + 1 - ky;
      if (ty_ < 0 || ty_ >= 7) continue;
      for (int kx = 0; kx < 3; ++kx) {
        int tx_ = xx + 1 - kx;
        if (tx_ < 0 || tx_ >= 7) continue;
        int pin = ty_ * 7 + tx_, t = ky * 3 + kx;
        __syncthreads();
        {
          const float* src = w3b + t * 4096;  // 64x64
          float* dl = &As[0][0];
#pragma unroll
          for (int r = 0; r < 4; ++r) {
            int f = r * 256 + tid;
            *(float4*)&dl[f * 4] = *(const float4*)&src[f * 4];
          }
        }
#pragma unroll
        for (int r = 0; r < 4; ++r) {  // 64 rows x 64
          int f = r * 256 + tid;
          int row = f >> 4, col = (f & 15) * 4;
          float4 v = {0.f, 0.f, 0.f, 0.f};
          int n = n0 + col;
          if (n + 4 <= NBp)
            v = *(const float4*)&cur[(size_t)(O3 + row * 49 + pin) * NBp + n];
          *(float4*)&Bs[row][col] = v;
        }
        __syncthreads();
#pragma unroll 16
        for (int k = 0; k < 64; ++k) FMA16(&As[k][c4], &Bs[k][n4]);
      }
    }
  }
  int n = n0 + n4;
  if (n + 4 <= NBp) {
#pragma unroll
    for (int i = 0; i < 4; ++i) {
      if (n == 784) acc[i][0] += b2[c4 + i];
      size_t off = (size_t)(O2 + (c4 + i) * 49 + p) * NBp + n;
      float4 pv = *(const float4*)&cur[off];
      float4 o;
      if (!POST) {
        o.x = 0.5f * pv.x + 0.5f * acc[i][0];
        o.y = 0.5f * pv.y + 0.5f * acc[i][1];
        o.z = 0.5f * pv.z + 0.5f * acc[i][2];
        o.w = 0.5f * pv.w + 0.5f * acc[i][3];
      } else {
        o.x = 0.5f * pv.x - acc[i][0];
        o.y = 0.5f * pv.y - acc[i][1];
        o.z = 0.5f * pv.z - acc[i][2];
        o.w = 0.5f * pv.w - acc[i][3];
      }
      *(float4*)&dst[off] = o;
    }
  }
}

// POST=0: s3' = 0.5 s3 + 0.5 (conv3(s2)+b3_aff + t4)
// POST=1: P3  = 0.5 s3 - (conv3(s2)+b3_aff)
template <int POST>
__global__ __launch_bounds__(256) void k_s3n(float* __restrict__ dst,
                                             const float* __restrict__ cur,
                                             const float* __restrict__ t4,
                                             const float* __restrict__ w3f,
                                             const float* __restrict__ b3) {
  __shared__ float As[64][64];
  __shared__ float Bs[64][64];
  const int tid = threadIdx.x;
  const int n4 = (tid & 15) * 4, c4 = (tid >> 4) * 4;
  const int n0 = blockIdx.x * 64;
  const int p = blockIdx.y;
  const int y = p / 7, xx = p % 7;
  float acc[4][4] = {};
  for (int ky = 0; ky < 3; ++ky) {
    int iy = y - 1 + ky;
    if (iy < 0 || iy >= 7) continue;
    for (int kx = 0; kx < 3; ++kx) {
      int ix = xx - 1 + kx;
      if (ix < 0 || ix >= 7) continue;
      int pin = iy * 7 + ix, t = ky * 3 + kx;
      __syncthreads();
      {
        const float* src = w3f + t * 4096;  // 64x64
        float* dl = &As[0][0];
#pragma unroll
        for (int r = 0; r < 4; ++r) {
          int f = r * 256 + tid;
          *(float4*)&dl[f * 4] = *(const float4*)&src[f * 4];
        }
      }
#pragma unroll
      for (int r = 0; r < 4; ++r) {
        int f = r * 256 + tid;
        int row = f >> 4, col = (f & 15) * 4;
        float4 v = {0.f, 0.f, 0.f, 0.f};
        int n = n0 + col;
        if (n + 4 <= NBp)
          v = *(const float4*)&cur[(size_t)(O2 + row * 49 + pin) * NBp + n];
        *(float4*)&Bs[row][col] = v;
      }
      __syncthreads();
#pragma unroll 16
      for (int k = 0; k < 64; ++k) FMA16(&As[k][c4], &Bs[k][n4]);
    }
  }
  int n = n0 + n4;
  if (n + 4 <= NBp) {
#pragma unroll
    for (int i = 0; i < 4; ++i) {
      if (n == 784) acc[i][0] += b3[c4 + i];
      size_t off = (size_t)(O3 + (c4 + i) * 49 + p) * NBp + n;
      float4 pv = *(const float4*)&cur[off];
      float4 o;
      if (!POST) {
        float4 tv = *(const float4*)&t4[(size_t)((c4 + i) * 49 + p) * NBp + n];
        o.x = 0.5f * pv.x + 0.5f * (acc[i][0] + tv.x);
        o.y = 0.5f * pv.y + 0.5f * (acc[i][1] + tv.y);
        o.z = 0.5f * pv.z + 0.5f * (acc[i][2] + tv.z);
        o.w = 0.5f * pv.w + 0.5f * (acc[i][3] + tv.w);
      } else {
        o.x = 0.5f * pv.x - acc[i][0];
        o.y = 0.5f * pv.y - acc[i][1];
        o.z = 0.5f * pv.z - acc[i][2];
        o.w = 0.5f * pv.w - acc[i][3];
      }
      *(float4*)&dst[off] = o;
    }
  }
}

// Register-blocked GEMM: C[m][n] = sum_k Aop[m][k] * B[k][n]
// TA=0: A row-major [m][k] (lda);  TA=1: A stored [k][m] (lda, phys width Aw).
// B row-major [k][n] (ldb). Tile 64x64, K-tile 32, micro 4x4, 256 threads.
// gridDim.z>1: writes partials C[z*M*ldc + ...] (no epilogue). Else epilogue:
//   v = alpha*(acc + biasN?[n] + (n==bias_col ? biasM?[m] : 0)) + beta*P0[m][n]
template <int TA>
__global__ __launch_bounds__(256) void gemm64(
    float* __restrict__ C, int ldc, const float* __restrict__ A, int lda, int Aw,
    const float* __restrict__ B, int ldb, int M, int N, int K, int kc, float alpha,
    float beta, const float* __restrict__ P0, int ldp, const float* __restrict__ biasM,
    int bias_col, const float* __restrict__ biasN) {
  __shared__ float As[32][68];
  __shared__ float Bs[32][68];
  const int tid = threadIdx.x;
  const int tx = tid & 15, ty = tid >> 4;
  const int m0 = blockIdx.y * 64, n0 = blockIdx.x * 64;
  const int z = blockIdx.z;
  int k0 = z * kc;
  const int kend = imin(K, k0 + kc);
  const int lk = tid >> 3, lm4 = (tid & 7) * 8;
  const int lmn = tid >> 2, lkq = (tid & 3) * 8;
  float acc[4][4] = {};
  for (; k0 < kend; k0 += 32) {
    __syncthreads();
    if (TA) {
      int gk = k0 + lk, gm = m0 + lm4;
#pragma unroll
      for (int h = 0; h < 2; ++h) {
        float4 v = {0.f, 0.f, 0.f, 0.f};
        if (gk < kend && gm + h * 4 + 4 <= Aw)
          v = *(const float4*)&A[(size_t)gk * lda + gm + h * 4];
        *(float4*)&As[lk][lm4 + h * 4] = v;
      }
    } else {
      int gm = m0 + lmn;
#pragma unroll
      for (int h = 0; h < 2; ++h) {
        int gk = k0 + lkq + h * 4;
        float4 v = {0.f, 0.f, 0.f, 0.f};
        if (gm < M && gk + 4 <= kend) v = *(const float4*)&A[(size_t)gm * lda + gk];
        As[lkq + h * 4 + 0][lmn] = v.x;
        As[lkq + h * 4 + 1][lmn] = v.y;
        As[lkq + h * 4 + 2][lmn] = v.z;
        As[lkq + h * 4 + 3][lmn] = v.w;
      }
    }
    {
      int gk = k0 + lk, gn = n0 + lm4;
#pragma unroll
      for (int h = 0; h < 2; ++h) {
        float4 v = {0.f, 0.f, 0.f, 0.f};
        if (gk < kend && gn + h * 4 + 4 <= N)
          v = *(const float4*)&B[(size_t)gk * ldb + gn + h * 4];
        *(float4*)&Bs[lk][lm4 + h * 4] = v;
      }
    }
    __syncthreads();
#pragma unroll 16
    for (int kk = 0; kk < 32; ++kk) FMA16(&As[kk][tx * 0 + ty * 4], &Bs[kk][tx * 4]);
  }
  if (gridDim.z > 1) {
    float* Cp = C + (size_t)z * M * ldc;
#pragma unroll
    for (int i = 0; i < 4; ++i) {
      int m = m0 + ty * 4 + i, n = n0 + tx * 4;
      if (m < M && n + 4 <= N) {
        float4 v = {acc[i][0], acc[i][1], acc[i][2], acc[i][3]};
        *(float4*)&Cp[(size_t)m * ldc + n] = v;
      }
    }
  } else {
#pragma unroll
    for (int i = 0; i < 4; ++i) {
      int m = m0 + ty * 4 + i, n = n0 + tx * 4;
      if (m >= M || n + 4 > N) continue;
      float4 v;
      float* vp = (float*)&v;
#pragma unroll
      for (int j = 0; j < 4; ++j) {
        float s = acc[i][j];
        if (biasN) s += biasN[n + j];
        if (biasM && (n + j) == bias_col) s += biasM[m];
        s *= alpha;
        if (P0) s += beta * P0[(size_t)m * ldp + n + j];
        vp[j] = s;
      }
      *(float4*)&C[(size_t)m * ldc + n] = v;
    }
  }
}

// C[m][n] = alpha*(sum_z part[z][m][n] + bias) + beta*P0[m][n]
__global__ void k_combine(float* __restrict__ C, int ldc, const float* __restrict__ part,
                          int M, int N, int KS, float alpha, float beta,
                          const float* __restrict__ P0, int ldp,
                          const float* __restrict__ biasM, int bias_col) {
  int total = M * N;
  for (int idx = blockIdx.x * blockDim.x + threadIdx.x; idx < total;
       idx += gridDim.x * blockDim.x) {
    int m = idx / N, n = idx % N;
    float s = 0.f;
    for (int zz = 0; zz < KS; ++zz) s += part[((size_t)zz * M + m) * N + n];
    if (biasM && n == bias_col) s += biasM[m];
    s *= alpha;
    if (P0) s += beta * P0[(size_t)m * ldp + n];
    C[(size_t)m * ldc + n] = s;
  }
}

// out[i] = 0.5||x_i||^2 - vb.x_i + sum_{j<784} x_ij Y[i,j] + Y[i,784]
__global__ void k_out(float* __restrict__ out, const float* __restrict__ x,
                      const float* __restrict__ vb, const float* __restrict__ Y, int Bn) {
  int wave = threadIdx.x >> 6, lane = threadIdx.x & 63;
  int i = blockIdx.x * 4 + wave;
  if (i >= Bn) return;
  const float* xi = x + (size_t)i * 784;
  const float* yi = Y + (size_t)i * NBp;
  float s = 0.f;
  for (int j = lane; j < 784; j += 64) {
    float xv = xi[j];
    s += xv * (0.5f * xv - vb[j] + yi[j]);
  }
  for (int off = 32; off; off >>= 1) s += __shfl_down(s, off);
  if (lane == 0) out[i] = s + yi[784];
}

extern "C" void kernel_launch(void* const* d_in, const int* in_sizes, int n_in, void* d_out,
                              int out_size, void* d_ws, size_t ws_size, hipStream_t stream) {
  const float* x  = (const float*)d_in[0];
  const float* vb = (const float*)d_in[1];
  const float* w1 = (const float*)d_in[2];
  const float* b1 = (const float*)d_in[3];
  const float* w2 = (const float*)d_in[4];
  const float* b2 = (const float*)d_in[5];
  const float* w3 = (const float*)d_in[6];
  const float* b3 = (const float*)d_in[7];
  const float* w4 = (const float*)d_in[8];
  const float* b4 = (const float*)d_in[9];
  int Bn = in_sizes[0] / 784;
  float* out = (float*)d_out;

  float* ws = (float*)d_ws;
  float* sA = ws;                                  // DT*NBp
  float* sB = sA + (size_t)DT * NBp;               // DT*NBp
  float* g  = sB + (size_t)DT * NBp;               // DT*NBp
  float* t4b = g + (size_t)DT * NBp;               // 3136*NBp; aliased by s4part (8*256*NBp)
  float* s4part = t4b;
  float* Hpart = t4b + (size_t)3136 * NBp;         // max(4*785*NBp, Bn*NBp); aliased by Ybuf
  float* Ybuf = Hpart;
  float* Hmat = Hpart + (size_t)4096 * NBp;        // 785*NBp
  float* w2f = Hmat + (size_t)NB * NBp;            // 9*32*64
  float* w2b = w2f + 9 * 32 * 64;                  // 9*64*32
  float* w3f = w2b + 9 * 64 * 32;                  // 9*64*64
  float* w3b = w3f + 9 * 64 * 64;                  // 9*64*64

  const int TB = 256;
  k_fill0<<<2048, TB, 0, stream>>>(sA, (size_t)DT * NBp);
  k_prep_w2<<<72, TB, 0, stream>>>(w2, w2f, w2b);
  k_prep_w3<<<144, TB, 0, stream>>>(w3, w3f, w3b);
  {
    size_t tot = (size_t)D1 * NBp;
    k_u1n<<<(int)((tot + TB - 1) / TB), TB, 0, stream>>>(g, w1, b1);
  }

  float* cur = sA;
  float* nxt = sB;
  for (int it = 0; it < NITER; ++it) {
    // t4 = W4^T s4  (TA GEMM: A=w4 [o][k] read transposed)
    gemm64<1><<<dim3(13, 49, 1), TB, 0, stream>>>(
        t4b, NBp, w4, 3136, 3136, cur + (size_t)O4 * NBp, NBp, 3136, NBp, 256, 256, 1.f,
        0.f, nullptr, 0, nullptr, -1, nullptr);
    k_s1n<<<dim3(7, 196), TB, 0, stream>>>(nxt, cur, g, w2b);
    k_s2n<0><<<dim3(13, 49), TB, 0, stream>>>(nxt, cur, w2f, w3b, b2);
    k_s3n<0><<<dim3(13, 49), TB, 0, stream>>>(nxt, cur, t4b, w3f, b3);
    // s4' = 0.5 s4 + 0.5 (W4 s3 + b4_aff): split-K partials + combine
    gemm64<0><<<dim3(13, 4, 8), TB, 0, stream>>>(
        s4part, NBp, w4, 3136, 0, cur + (size_t)O3 * NBp, NBp, 256, NBp, 3136, 416, 0.f,
        0.f, nullptr, 0, nullptr, -1, nullptr);
    k_combine<<<788, TB, 0, stream>>>(nxt + (size_t)O4 * NBp, NBp, s4part, 256, NBp, 8,
                                      0.5f, 0.5f, cur + (size_t)O4 * NBp, NBp, b4, 784);
    float* tmp = cur; cur = nxt; nxt = tmp;
  }

  // post-fields: P = 0.5*S - G  (into g)
  {
    size_t tot = (size_t)D1 * NBp;
    k_p1n<<<(int)((tot + TB - 1) / TB), TB, 0, stream>>>(g, cur);
  }
  k_s2n<1><<<dim3(13, 49), TB, 0, stream>>>(g, cur, w2f, w3b, b2);
  k_s3n<1><<<dim3(13, 49), TB, 0, stream>>>(g, cur, t4b, w3f, b3);
  gemm64<0><<<dim3(13, 4, 8), TB, 0, stream>>>(
      s4part, NBp, w4, 3136, 0, cur + (size_t)O3 * NBp, NBp, 256, NBp, 3136, 416, 0.f, 0.f,
      nullptr, 0, nullptr, -1, nullptr);
  k_combine<<<788, TB, 0, stream>>>(g + (size_t)O4 * NBp, NBp, s4part, 256, NBp, 8, -1.f,
                                    0.5f, cur + (size_t)O4 * NBp, NBp, b4, 784);

  // H[j][k] = sum_d P[d][j] S[d][k]  (TA GEMM, split-K 4)
  gemm64<1><<<dim3(13, 13, 4), TB, 0, stream>>>(Hpart, NBp, g, NBp, NBp, cur, NBp, NB, NBp,
                                                DT, 3200, 0.f, 0.f, nullptr, 0, nullptr, -1,
                                                nullptr);
  k_combine<<<2048, TB, 0, stream>>>(Hmat, NBp, Hpart, NB, NBp, 4, 1.f, 0.f, nullptr, 0,
                                     nullptr, -1);

  // Y[i][k] = sum_{j<784} x[i][j] H[j][k] + H[784][k]
  gemm64<0><<<dim3(13, 64, 1), TB, 0, stream>>>(Ybuf, NBp, x, 784, 0, Hmat, NBp, Bn, NBp,
                                                784, 784, 1.f, 0.f, nullptr, 0, nullptr, -1,
                                                Hmat + (size_t)784 * NBp);
  k_out<<<(Bn + 3) / 4, TB, 0, stream>>>(out, x, vb, Ybuf, Bn);
}

// Round 3
// 9878.632 us; speedup vs baseline: 10.8223x; 1.3491x over previous
//
#include <hip/hip_runtime.h>
#include <cstddef>

// Basis-propagation + bf16 hi/lo split MFMA.
// State S[pos][n][c] channel-minor, bf16 hi plane + lo plane (+SELEMS).
// n in [0,832): 784 pixel basis + col 784 = affine (biases) + 47 zero pads.
// Every op is a tap-GEMM: D[m=c_out][n] += W[m][k] * S[k=c_in][n], 3 MFMAs per
// K-step (hi*hi + hi*lo + lo*hi), fp32 accum. E(x) = 0.5||x||^2 - vb.x + x~'Hx~.

typedef unsigned short ushort_t;
typedef __attribute__((ext_vector_type(8))) short bf8_t;   // 8 bf16
typedef __attribute__((ext_vector_type(4))) float f4_t;

#define MFMA16 __builtin_amdgcn_mfma_f32_16x16x32_bf16

#define NBn 832
#define NITER 50
#define SELEMS 10649600u   // total state elems per plane
#define R1 0u              // s1: 196 pos x 832 n x 32 c   (pos stride 26624)
#define R2 5218304u        // s2: 49 pos x 832 n x 64 c    (pos stride 53248)
#define R3 7827456u        // s3: 49 x 832 x 64
#define R4 10436608u       // s4: 832 n x 256 o
#define GPL 5218304u       // u1/G plane size (R1-shaped)

// packed weights (elems; each matrix = [hi plane][lo plane])
#define W2F_OFF 0u         // [t][co 64][ci 32]
#define W2B_OFF 36864u     // [t][ci 32][co 64]
#define W3F_OFF 73728u     // [t][co 64][ci 64]
#define W3B_OFF 147456u    // [t][ci 64][co 64]
#define W4P_OFF 221184u    // [p 49][c 64][o 256]
#define W4Q_OFF 1826816u   // [o 256][p*64+c 3136]
#define W2PL 18432u
#define W3PL 36864u
#define W4PL 802816u
#define WPTOT 3432448u

__device__ __forceinline__ int imin(int a, int b) { return a < b ? a : b; }

__device__ __forceinline__ void bsplit(float v, ushort_t& h, ushort_t& lo) {
  union { float f; unsigned u; } a; a.f = v;
  unsigned uh = (a.u + 0x7fffu + ((a.u >> 16) & 1u)) & 0xffff0000u;
  h = (ushort_t)(uh >> 16);
  union { unsigned u; float f; } b; b.u = uh;
  float r = v - b.f;
  union { float f; unsigned u; } c; c.f = r;
  lo = (ushort_t)((c.u + 0x7fffu + ((c.u >> 16) & 1u)) >> 16);
}

__device__ __forceinline__ float bjoin(ushort_t h, ushort_t l) {
  union { unsigned u; float f; } a, b;
  a.u = ((unsigned)h) << 16; b.u = ((unsigned)l) << 16;
  return a.f + b.f;
}

// one K=32 MFMA step for NSUB n-subtiles: A row-major [m][K], B = state [n][c]
template <int NSUB>
__device__ __forceinline__ void kstep(f4_t* acc, const ushort_t* ap, size_t apl,
                                      const ushort_t* bp, size_t bpl, int bstride) {
  bf8_t ah = *(const bf8_t*)ap;
  bf8_t al = *(const bf8_t*)(ap + apl);
#pragma unroll
  for (int j = 0; j < NSUB; ++j) {
    const ushort_t* b = bp + (size_t)j * 16 * bstride;
    bf8_t bh = *(const bf8_t*)b;
    bf8_t bl = *(const bf8_t*)(b + bpl);
    acc[j] = MFMA16(ah, bh, acc[j], 0, 0, 0);
    acc[j] = MFMA16(ah, bl, acc[j], 0, 0, 0);
    acc[j] = MFMA16(al, bh, acc[j], 0, 0, 0);
  }
}

__global__ void k_fill0(float* p, unsigned n) {
  for (unsigned i = blockIdx.x * blockDim.x + threadIdx.x; i < n;
       i += gridDim.x * blockDim.x)
    p[i] = 0.f;
}

__global__ void k_pack2(const float* __restrict__ w2, ushort_t* __restrict__ WP) {
  int idx = blockIdx.x * blockDim.x + threadIdx.x;
  if (idx >= 18432) return;
  int co = idx / 288, rem = idx % 288, ci = rem / 9, t = rem % 9;
  ushort_t h, l; bsplit(w2[idx], h, l);
  unsigned f = W2F_OFF + t * 2048 + co * 32 + ci;
  unsigned b = W2B_OFF + t * 2048 + ci * 64 + co;
  WP[f] = h; WP[f + W2PL] = l;
  WP[b] = h; WP[b + W2PL] = l;
}

__global__ void k_pack3(const float* __restrict__ w3, ushort_t* __restrict__ WP) {
  int idx = blockIdx.x * blockDim.x + threadIdx.x;
  if (idx >= 36864) return;
  int co = idx / 576, rem = idx % 576, ci = rem / 9, t = rem % 9;
  ushort_t h, l; bsplit(w3[idx], h, l);
  unsigned f = W3F_OFF + t * 4096 + co * 64 + ci;
  unsigned b = W3B_OFF + t * 4096 + ci * 64 + co;
  WP[f] = h; WP[f + W3PL] = l;
  WP[b] = h; WP[b + W3PL] = l;
}

__global__ void k_pack4(const float* __restrict__ w4, ushort_t* __restrict__ WP) {
  int idx = blockIdx.x * blockDim.x + threadIdx.x;
  if (idx >= 802816) return;
  int o = idx / 3136, kk = idx % 3136, c = kk / 49, p = kk % 49;
  ushort_t h, l; bsplit(w4[idx], h, l);
  unsigned a = W4P_OFF + p * 16384 + c * 256 + o;
  unsigned b = W4Q_OFF + o * 3136 + p * 64 + c;
  WP[a] = h; WP[a + W4PL] = l;
  WP[b] = h; WP[b + W4PL] = l;
}

// u1[q][n][c]: conv1 of basis vector n (n==784 -> b1, pads 0), split bf16
__global__ void k_u1b(ushort_t* __restrict__ G, const float* __restrict__ w1,
                      const float* __restrict__ b1) {
  unsigned idx = blockIdx.x * blockDim.x + threadIdx.x;
  if (idx >= GPL) return;
  int q = idx / 26624, rem = idx % 26624, n = rem / 32, c = rem % 32;
  int oy = q / 14, ox = q % 14;
  float v = 0.f;
  if (n < 784) {
    int py = n / 28, px = n % 28;
    int ky = py - (2 * oy - 1), kx = px - (2 * ox - 1);
    if (ky >= 0 && ky < 3 && kx >= 0 && kx < 3) v = w1[c * 9 + ky * 3 + kx];
  } else if (n == 784) {
    v = b1[c];
  }
  ushort_t h, l; bsplit(v, h, l);
  G[idx] = h; G[idx + GPL] = l;
}

// P1 = 0.5*s1_final - u1  (elementwise on R1, 8 elems/thread)
__global__ void k_p1(ushort_t* __restrict__ D, const ushort_t* __restrict__ S,
                     const ushort_t* __restrict__ G) {
  unsigned g8 = (blockIdx.x * blockDim.x + threadIdx.x) * 8;
  if (g8 >= GPL) return;
  bf8_t oh = *(const bf8_t*)&S[g8], ol = *(const bf8_t*)&S[g8 + SELEMS];
  bf8_t gh = *(const bf8_t*)&G[g8], gl = *(const bf8_t*)&G[g8 + GPL];
  bf8_t rh, rl;
#pragma unroll
  for (int e = 0; e < 8; ++e) {
    float v = 0.5f * bjoin((ushort_t)oh[e], (ushort_t)ol[e]) -
              bjoin((ushort_t)gh[e], (ushort_t)gl[e]);
    ushort_t h, l; bsplit(v, h, l);
    rh[e] = (short)h; rl[e] = (short)l;
  }
  *(bf8_t*)&D[g8] = rh;
  *(bf8_t*)&D[g8 + SELEMS] = rl;
}

// shared epilogue for C=64 regions: LDS f32 tile [n 64][c 64] -> hi/lo out
__device__ __forceinline__ void epi_c64(ushort_t* __restrict__ D,
                                        const ushort_t* __restrict__ S,
                                        const float* __restrict__ Lt, size_t rbase,
                                        int pos, int n0, const float* __restrict__ bias,
                                        int post) {
  int tid = threadIdx.x;
  int nl = tid >> 2, cq = (tid & 3) * 16;
  int n = n0 + nl;
  size_t off = rbase + (size_t)pos * 53248 + (size_t)n * 64 + cq;
  const float* lp = Lt + nl * 65 + cq;
#pragma unroll
  for (int half = 0; half < 2; ++half) {
    size_t o8 = off + half * 8;
    bf8_t oh = *(const bf8_t*)&S[o8], ol = *(const bf8_t*)&S[o8 + SELEMS];
    bf8_t rh, rl;
#pragma unroll
    for (int e = 0; e < 8; ++e) {
      float v = lp[half * 8 + e];
      if (n == 784) v += bias[cq + half * 8 + e];
      float old = bjoin((ushort_t)oh[e], (ushort_t)ol[e]);
      float nv = post ? 0.5f * old - v : 0.5f * old + 0.5f * v;
      ushort_t h, l; bsplit(nv, h, l);
      rh[e] = (short)h; rl[e] = (short)l;
    }
    *(bf8_t*)&D[o8] = rh;
    *(bf8_t*)&D[o8 + SELEMS] = rl;
  }
}

// mega update kernel: role-dispatch. post=0: blocks [s1 2548][s2 637][s3 637][s4 416]
// post=1: [P2 637][P3 637][P4-partials 416]
__global__ __launch_bounds__(256) void k_mega(
    const ushort_t* __restrict__ S, ushort_t* __restrict__ D,
    float* __restrict__ s4part, const ushort_t* __restrict__ G,
    const ushort_t* __restrict__ WP, const float* __restrict__ b2,
    const float* __restrict__ b3, int post) {
  __shared__ float Lt[64 * 65];
  int b = blockIdx.x;
  int tid = threadIdx.x, l = tid & 63, w = tid >> 6;
  int koff = (l >> 4) * 8;
  int role, rb;
  if (!post) {
    if (b < 2548) { role = 0; rb = b; }
    else if (b < 3185) { role = 1; rb = b - 2548; }
    else if (b < 3822) { role = 2; rb = b - 3185; }
    else { role = 3; rb = b - 3822; }
  } else {
    if (b < 637) { role = 1; rb = b; }
    else if (b < 1274) { role = 2; rb = b - 637; }
    else { role = 3; rb = b - 1274; }
  }

  if (role == 0) {
    // s1' = 0.5 s1 + 0.5 (u1 + conv2^T s2); tile 32c x 64n at position q
    int ntile = rb % 13, q = rb / 13;
    int n0 = ntile * 64, y = q / 14, x = q % 14;
    int mloc = (w & 1) * 16;
    int nbase = n0 + (w >> 1) * 32;
    f4_t acc[2] = {{0.f, 0.f, 0.f, 0.f}, {0.f, 0.f, 0.f, 0.f}};
    for (int ky = 0; ky < 3; ++ky) {
      int ty = y + 1 - ky;
      if ((ty & 1) || ty < 0 || ty >= 14) continue;
      int oy = ty >> 1;
      for (int kx = 0; kx < 3; ++kx) {
        int tx = x + 1 - kx;
        if ((tx & 1) || tx < 0 || tx >= 14) continue;
        int ox = tx >> 1;
        int t = ky * 3 + kx, pin = oy * 7 + ox;
        const ushort_t* A = WP + W2B_OFF + t * 2048 + (mloc + (l & 15)) * 64 + koff;
        const ushort_t* B = S + R2 + (size_t)pin * 53248 +
                            (size_t)(nbase + (l & 15)) * 64 + koff;
        kstep<2>(acc, A, W2PL, B, SELEMS, 64);
        kstep<2>(acc, A + 32, W2PL, B + 32, SELEMS, 64);
      }
    }
#pragma unroll
    for (int j = 0; j < 2; ++j)
#pragma unroll
      for (int r = 0; r < 4; ++r)
        Lt[(32 * (w >> 1) + 16 * j + (l & 15)) * 33 + mloc + (l >> 4) * 4 + r] =
            acc[j][r];
    __syncthreads();
    int nl = tid >> 2, cq = (tid & 3) * 8;
    int n = n0 + nl;
    size_t off = (size_t)q * 26624 + (size_t)n * 32 + cq;
    bf8_t oh = *(const bf8_t*)&S[off], ol = *(const bf8_t*)&S[off + SELEMS];
    bf8_t gh = *(const bf8_t*)&G[off], gl = *(const bf8_t*)&G[off + GPL];
    const float* lp = Lt + nl * 33 + cq;
    bf8_t rh, rl;
#pragma unroll
    for (int e = 0; e < 8; ++e) {
      float old = bjoin((ushort_t)oh[e], (ushort_t)ol[e]);
      float u = bjoin((ushort_t)gh[e], (ushort_t)gl[e]);
      float nv = 0.5f * old + 0.5f * (lp[e] + u);
      ushort_t h, lo; bsplit(nv, h, lo);
      rh[e] = (short)h; rl[e] = (short)lo;
    }
    *(bf8_t*)&D[off] = rh;
    *(bf8_t*)&D[off + SELEMS] = rl;
  } else if (role == 1) {
    // s2' = 0.5 s2 + 0.5(conv2(s1)+b2 + conv3^T s3)  |  P2 = 0.5 s2 - (conv2+b2)
    int ntile = rb % 13, p = rb / 13;
    int n0 = ntile * 64, y = p / 7, xx = p % 7;
    f4_t acc[4] = {{0.f,0.f,0.f,0.f},{0.f,0.f,0.f,0.f},{0.f,0.f,0.f,0.f},{0.f,0.f,0.f,0.f}};
    int arow = w * 16 + (l & 15), nrow = n0 + (l & 15);
    for (int ky = 0; ky < 3; ++ky) {
      int iy = 2 * y - 1 + ky;
      if (iy < 0 || iy >= 14) continue;
      for (int kx = 0; kx < 3; ++kx) {
        int ix = 2 * xx - 1 + kx;
        if (ix < 0 || ix >= 14) continue;
        int t = ky * 3 + kx, pin = iy * 14 + ix;
        const ushort_t* A = WP + W2F_OFF + t * 2048 + arow * 32 + koff;
        const ushort_t* B = S + R1 + (size_t)pin * 26624 + (size_t)nrow * 32 + koff;
        kstep<4>(acc, A, W2PL, B, SELEMS, 32);
      }
    }
    if (!post) {
      for (int ky = 0; ky < 3; ++ky) {
        int ty = y + 1 - ky;
        if (ty < 0 || ty >= 7) continue;
        for (int kx = 0; kx < 3; ++kx) {
          int tx = xx + 1 - kx;
          if (tx < 0 || tx >= 7) continue;
          int t = ky * 3 + kx, pin = ty * 7 + tx;
          const ushort_t* A = WP + W3B_OFF + t * 4096 + arow * 64 + koff;
          const ushort_t* B = S + R3 + (size_t)pin * 53248 + (size_t)nrow * 64 + koff;
          kstep<4>(acc, A, W3PL, B, SELEMS, 64);
          kstep<4>(acc, A + 32, W3PL, B + 32, SELEMS, 64);
        }
      }
    }
#pragma unroll
    for (int j = 0; j < 4; ++j)
#pragma unroll
      for (int r = 0; r < 4; ++r)
        Lt[(16 * j + (l & 15)) * 65 + w * 16 + (l >> 4) * 4 + r] = acc[j][r];
    __syncthreads();
    epi_c64(D, S, Lt, R2, p, n0, b2, post);
  } else if (role == 2) {
    // s3' = 0.5 s3 + 0.5(conv3(s2)+b3 + W4^T s4)  |  P3 = 0.5 s3 - (conv3+b3)
    int ntile = rb % 13, p = rb / 13;
    int n0 = ntile * 64, y = p / 7, xx = p % 7;
    f4_t acc[4] = {{0.f,0.f,0.f,0.f},{0.f,0.f,0.f,0.f},{0.f,0.f,0.f,0.f},{0.f,0.f,0.f,0.f}};
    int arow = w * 16 + (l & 15), nrow = n0 + (l & 15);
    for (int ky = 0; ky < 3; ++ky) {
      int iy = y - 1 + ky;
      if (iy < 0 || iy >= 7) continue;
      for (int kx = 0; kx < 3; ++kx) {
        int ix = xx - 1 + kx;
        if (ix < 0 || ix >= 7) continue;
        int t = ky * 3 + kx, pin = iy * 7 + ix;
        const ushort_t* A = WP + W3F_OFF + t * 4096 + arow * 64 + koff;
        const ushort_t* B = S + R2 + (size_t)pin * 53248 + (size_t)nrow * 64 + koff;
        kstep<4>(acc, A, W3PL, B, SELEMS, 64);
        kstep<4>(acc, A + 32, W3PL, B + 32, SELEMS, 64);
      }
    }
    if (!post) {
      const ushort_t* A = WP + W4P_OFF + p * 16384 + arow * 256 + koff;
      const ushort_t* B = S + R4 + (size_t)nrow * 256 + koff;
#pragma unroll
      for (int ks = 0; ks < 8; ++ks)
        kstep<4>(acc, A + ks * 32, W4PL, B + ks * 32, SELEMS, 256);
    }
#pragma unroll
    for (int j = 0; j < 4; ++j)
#pragma unroll
      for (int r = 0; r < 4; ++r)
        Lt[(16 * j + (l & 15)) * 65 + w * 16 + (l >> 4) * 4 + r] = acc[j][r];
    __syncthreads();
    epi_c64(D, S, Lt, R3, p, n0, b3, post);
  } else {
    // s4 partials: acc = W4 s3 (split-K over z=8) -> s4part[z][n][256]
    int z = rb / 52, rr = rb % 52;
    int otile = rr / 13, ntile = rr % 13;
    int m0 = otile * 64, n0 = ntile * 64;
    f4_t acc[4] = {{0.f,0.f,0.f,0.f},{0.f,0.f,0.f,0.f},{0.f,0.f,0.f,0.f},{0.f,0.f,0.f,0.f}};
    int arow = m0 + w * 16 + (l & 15), nrow = n0 + (l & 15);
    int sbeg = (98 * z) / 8, send = (98 * (z + 1)) / 8;
    for (int s = sbeg; s < send; ++s) {
      int k0 = s * 32;
      const ushort_t* A = WP + W4Q_OFF + (size_t)arow * 3136 + k0 + koff;
      const ushort_t* B = S + R3 + (size_t)(k0 >> 6) * 53248 + (size_t)nrow * 64 +
                          (k0 & 63) + koff;
      kstep<4>(acc, A, W4PL, B, SELEMS, 64);
    }
#pragma unroll
    for (int j = 0; j < 4; ++j)
#pragma unroll
      for (int r = 0; r < 4; ++r)
        s4part[((size_t)z * NBn + n0 + 16 * j + (l & 15)) * 256 + m0 + w * 16 +
               (l >> 4) * 4 + r] = acc[j][r];
  }
}

// s4 combine: sum 8 partials -> update (iter) or P4 (post)
__global__ void k_comb4(ushort_t* __restrict__ D, const ushort_t* __restrict__ S,
                        const float* __restrict__ part, const float* __restrict__ b4,
                        int post) {
  int g = blockIdx.x * blockDim.x + threadIdx.x;  // 26624 threads
  int n = g >> 5, oq = (g & 31) * 8;
  float a[8] = {};
#pragma unroll
  for (int z = 0; z < 8; ++z) {
    const float* p = part + ((size_t)z * NBn + n) * 256 + oq;
    float4 v0 = *(const float4*)p, v1 = *(const float4*)(p + 4);
    a[0] += v0.x; a[1] += v0.y; a[2] += v0.z; a[3] += v0.w;
    a[4] += v1.x; a[5] += v1.y; a[6] += v1.z; a[7] += v1.w;
  }
  size_t off = R4 + (size_t)n * 256 + oq;
  bf8_t oh = *(const bf8_t*)&S[off], ol = *(const bf8_t*)&S[off + SELEMS];
  bf8_t rh, rl;
#pragma unroll
  for (int e = 0; e < 8; ++e) {
    float v = a[e];
    if (n == 784) v += b4[oq + e];
    float old = bjoin((ushort_t)oh[e], (ushort_t)ol[e]);
    float nv = post ? 0.5f * old - v : 0.5f * old + 0.5f * v;
    ushort_t h, l; bsplit(nv, h, l);
    rh[e] = (short)h; rl[e] = (short)l;
  }
  *(bf8_t*)&D[off] = rh;
  *(bf8_t*)&D[off + SELEMS] = rl;
}

// H[j][k] = sum_d P[d][j] S[d][k] — MFMA over the channel-minor layout, split-K 6
__device__ __forceinline__ void hstep(int s, size_t& base, int& C, int& c0) {
  if (s < 196) { base = R1 + (size_t)s * 26624; C = 32; c0 = 0; }
  else if (s < 294) { int u = s - 196; base = R2 + (size_t)(u >> 1) * 53248; C = 64; c0 = (u & 1) * 32; }
  else if (s < 392) { int u = s - 294; base = R3 + (size_t)(u >> 1) * 53248; C = 64; c0 = (u & 1) * 32; }
  else { base = R4; C = 256; c0 = (s - 392) * 32; }
}

__global__ __launch_bounds__(256) void k_hgemm(float* __restrict__ Hp,
                                               const ushort_t* __restrict__ P,
                                               const ushort_t* __restrict__ S) {
  int tid = threadIdx.x, l = tid & 63, w = tid >> 6;
  int m0 = blockIdx.y * 64 + w * 16, n0 = blockIdx.x * 64;
  int z = blockIdx.z;
  int koff = (l >> 4) * 8;
  int s0 = (400 * z) / 6, s1e = (400 * (z + 1)) / 6;
  f4_t acc[4] = {{0.f,0.f,0.f,0.f},{0.f,0.f,0.f,0.f},{0.f,0.f,0.f,0.f},{0.f,0.f,0.f,0.f}};
  for (int s = s0; s < s1e; ++s) {
    size_t base; int C, c0;
    hstep(s, base, C, c0);
    const ushort_t* A = P + base + (size_t)(m0 + (l & 15)) * C + c0 + koff;
    const ushort_t* B = S + base + (size_t)(n0 + (l & 15)) * C + c0 + koff;
    kstep<4>(acc, A, SELEMS, B, SELEMS, C);
  }
#pragma unroll
  for (int j = 0; j < 4; ++j)
#pragma unroll
    for (int r = 0; r < 4; ++r)
      Hp[((size_t)z * NBn + m0 + (l >> 4) * 4 + r) * NBn + n0 + 16 * j + (l & 15)] =
          acc[j][r];
}

// C[m][n] = alpha*(sum_z part[z][m][n]) + ...
__global__ void k_combine(float* __restrict__ C, int ldc, const float* __restrict__ part,
                          int M, int N, int KS, float alpha, float beta,
                          const float* __restrict__ P0, int ldp,
                          const float* __restrict__ biasM, int bias_col) {
  int total = M * N;
  for (int idx = blockIdx.x * blockDim.x + threadIdx.x; idx < total;
       idx += gridDim.x * blockDim.x) {
    int m = idx / N, n = idx % N;
    float s = 0.f;
    for (int zz = 0; zz < KS; ++zz) s += part[((size_t)zz * M + m) * N + n];
    if (biasM && n == bias_col) s += biasM[m];
    s *= alpha;
    if (P0) s += beta * P0[(size_t)m * ldp + n];
    C[(size_t)m * ldc + n] = s;
  }
}

// fp32 register-blocked GEMM (round-1, TA=0 path): C = alpha*(A*B + biasN) + beta*P0
template <int TA>
__global__ __launch_bounds__(256) void gemm64(
    float* __restrict__ C, int ldc, const float* __restrict__ A, int lda, int Aw,
    const float* __restrict__ B, int ldb, int M, int N, int K, int kc, float alpha,
    float beta, const float* __restrict__ P0, int ldp, const float* __restrict__ biasM,
    int bias_col, const float* __restrict__ biasN) {
  __shared__ float As[32][68];
  __shared__ float Bs[32][68];
  const int tid = threadIdx.x;
  const int tx = tid & 15, ty = tid >> 4;
  const int m0 = blockIdx.y * 64, n0 = blockIdx.x * 64;
  const int z = blockIdx.z;
  int k0 = z * kc;
  const int kend = imin(K, k0 + kc);
  const int lk = tid >> 3, lm4 = (tid & 7) * 8;
  const int lmn = tid >> 2, lkq = (tid & 3) * 8;
  float acc[4][4] = {};
  for (; k0 < kend; k0 += 32) {
    __syncthreads();
    {
      int gm = m0 + lmn;
#pragma unroll
      for (int h = 0; h < 2; ++h) {
        int gk = k0 + lkq + h * 4;
        float4 v = {0.f, 0.f, 0.f, 0.f};
        if (gm < M && gk + 4 <= kend) v = *(const float4*)&A[(size_t)gm * lda + gk];
        As[lkq + h * 4 + 0][lmn] = v.x;
        As[lkq + h * 4 + 1][lmn] = v.y;
        As[lkq + h * 4 + 2][lmn] = v.z;
        As[lkq + h * 4 + 3][lmn] = v.w;
      }
    }
    {
      int gk = k0 + lk, gn = n0 + lm4;
#pragma unroll
      for (int h = 0; h < 2; ++h) {
        float4 v = {0.f, 0.f, 0.f, 0.f};
        if (gk < kend && gn + h * 4 + 4 <= N)
          v = *(const float4*)&B[(size_t)gk * ldb + gn + h * 4];
        *(float4*)&Bs[lk][lm4 + h * 4] = v;
      }
    }
    __syncthreads();
#pragma unroll 16
    for (int kk = 0; kk < 32; ++kk) {
      float4 a_ = *(const float4*)&As[kk][ty * 4];
      float4 b_ = *(const float4*)&Bs[kk][tx * 4];
      acc[0][0] += a_.x * b_.x; acc[0][1] += a_.x * b_.y;
      acc[0][2] += a_.x * b_.z; acc[0][3] += a_.x * b_.w;
      acc[1][0] += a_.y * b_.x; acc[1][1] += a_.y * b_.y;
      acc[1][2] += a_.y * b_.z; acc[1][3] += a_.y * b_.w;
      acc[2][0] += a_.z * b_.x; acc[2][1] += a_.z * b_.y;
      acc[2][2] += a_.z * b_.z; acc[2][3] += a_.z * b_.w;
      acc[3][0] += a_.w * b_.x; acc[3][1] += a_.w * b_.y;
      acc[3][2] += a_.w * b_.z; acc[3][3] += a_.w * b_.w;
    }
  }
#pragma unroll
  for (int i = 0; i < 4; ++i) {
    int m = m0 + ty * 4 + i, n = n0 + tx * 4;
    if (m >= M || n + 4 > N) continue;
    float4 v;
    float* vp = (float*)&v;
#pragma unroll
    for (int j = 0; j < 4; ++j) {
      float s = acc[i][j];
      if (biasN) s += biasN[n + j];
      s *= alpha;
      if (P0) s += beta * P0[(size_t)m * ldp + n + j];
      vp[j] = s;
    }
    *(float4*)&C[(size_t)m * ldc + n] = v;
  }
}

// out[i] = 0.5||x_i||^2 - vb.x_i + sum_{j<784} x_ij Y[i,j] + Y[i,784]
__global__ void k_out(float* __restrict__ out, const float* __restrict__ x,
                      const float* __restrict__ vb, const float* __restrict__ Y, int Bn) {
  int wave = threadIdx.x >> 6, lane = threadIdx.x & 63;
  int i = blockIdx.x * 4 + wave;
  if (i >= Bn) return;
  const float* xi = x + (size_t)i * 784;
  const float* yi = Y + (size_t)i * NBn;
  float s = 0.f;
  for (int j = lane; j < 784; j += 64) {
    float xv = xi[j];
    s += xv * (0.5f * xv - vb[j] + yi[j]);
  }
  for (int off = 32; off; off >>= 1) s += __shfl_down(s, off);
  if (lane == 0) out[i] = s + yi[784];
}

extern "C" void kernel_launch(void* const* d_in, const int* in_sizes, int n_in, void* d_out,
                              int out_size, void* d_ws, size_t ws_size, hipStream_t stream) {
  const float* x  = (const float*)d_in[0];
  const float* vb = (const float*)d_in[1];
  const float* w1 = (const float*)d_in[2];
  const float* b1 = (const float*)d_in[3];
  const float* w2 = (const float*)d_in[4];
  const float* b2 = (const float*)d_in[5];
  const float* w3 = (const float*)d_in[6];
  const float* b3 = (const float*)d_in[7];
  const float* w4 = (const float*)d_in[8];
  const float* b4 = (const float*)d_in[9];
  int Bn = in_sizes[0] / 784;
  float* out = (float*)d_out;

  ushort_t* Sa = (ushort_t*)d_ws;                    // 2*SELEMS
  ushort_t* Sb = Sa + (size_t)2 * SELEMS;            // 2*SELEMS
  ushort_t* G  = Sb + (size_t)2 * SELEMS;            // 2*GPL
  ushort_t* WP = G + (size_t)2 * GPL;                // WPTOT
  float* Hpart = (float*)(WP + WPTOT);               // 6*832*832 f32 (aliases below)
  float* s4part = Hpart;                             // 8*832*256 f32
  float* Ybuf = Hpart;                               // Bn*832 f32
  float* Hmat = Hpart + (size_t)6 * NBn * NBn;       // 832*832 f32

  const int TB = 256;
  k_fill0<<<2048, TB, 0, stream>>>((float*)Sa, SELEMS);  // zero hi+lo planes
  k_pack2<<<72, TB, 0, stream>>>(w2, WP);
  k_pack3<<<144, TB, 0, stream>>>(w3, WP);
  k_pack4<<<3136, TB, 0, stream>>>(w4, WP);
  k_u1b<<<20384, TB, 0, stream>>>(G, w1, b1);

  ushort_t* cur = Sa;
  ushort_t* nxt = Sb;
  for (int it = 0; it < NITER; ++it) {
    k_mega<<<4238, TB, 0, stream>>>(cur, nxt, s4part, G, WP, b2, b3, 0);
    k_comb4<<<104, TB, 0, stream>>>(nxt, cur, s4part, b4, 0);
    ushort_t* t = cur; cur = nxt; nxt = t;
  }

  // post fields P into nxt
  k_p1<<<2548, TB, 0, stream>>>(nxt, cur, G);
  k_mega<<<1690, TB, 0, stream>>>(cur, nxt, s4part, G, WP, b2, b3, 1);
  k_comb4<<<104, TB, 0, stream>>>(nxt, cur, s4part, b4, 1);

  // H = P' S  (split-K 6) -> Hmat
  k_hgemm<<<dim3(13, 13, 6), TB, 0, stream>>>(Hpart, nxt, cur);
  k_combine<<<2048, TB, 0, stream>>>(Hmat, NBn, Hpart, NBn, NBn, 6, 1.f, 0.f, nullptr, 0,
                                     nullptr, -1);

  // Y = x~ * H  (fp32), then out
  gemm64<0><<<dim3(13, (Bn + 63) / 64), TB, 0, stream>>>(
      Ybuf, NBn, x, 784, 0, Hmat, NBn, Bn, NBn, 784, 784, 1.f, 0.f, nullptr, 0, nullptr,
      -1, Hmat + (size_t)784 * NBn);
  k_out<<<(Bn + 3) / 4, TB, 0, stream>>>(out, x, vb, Ybuf, Bn);
}

// Round 4
// 4804.476 us; speedup vs baseline: 22.2521x; 2.0561x over previous
//
#include <hip/hip_runtime.h>
#include <cstddef>

// Basis-propagation + bf16 hi/lo split MFMA, pipelined LDS-staged tap-GEMMs.
// State S[pos][n][c] channel-minor, bf16 hi plane + lo plane (+SELG), with
// zero guard bands between regions so every conv tap is address-safe.
// n in [0,832): 784 pixel basis + col 784 = affine (biases) + 47 zero pads.
// Invalid taps use a zero-weight block (A=0 -> exact 0 contribution).

typedef unsigned short ushort_t;
typedef __attribute__((ext_vector_type(8))) short bf8_t;   // 8 bf16
typedef __attribute__((ext_vector_type(4))) float f4_t;

#define MFMA16 __builtin_amdgcn_mfma_f32_16x16x32_bf16

#define NBn 832
#define NITER 50
#define GPL 5218304u       // u1/G plane size (196*26624, no guards)

// state plane geometry (elems), with guards:
// [g1pre 15*26624][s1 196*26624][g2pre 8*53248][s2 49*53248][g2post 15*53248]
// [g3pre 8*53248][s3 49*53248][g3post 8*53248][s4 832*256]
#define SELG 13125632u
#define R1G 399360
#define R2G 6043648
#define R3G 9877504
#define R4G 12912640

// packed weights (elems; each matrix = [hi plane][lo plane])
#define W2F_OFF 0u         // [t][co 64][ci 32]
#define W2B_OFF 36864u     // [t][ci 32][co 64]
#define W3F_OFF 73728u     // [t][co 64][ci 64]
#define W3B_OFF 147456u    // [t][ci 64][co 64]
#define W4P_OFF 221184u    // [p 49][c 64][o 256]
#define W4Q_OFF 1826816u   // [o 256][p*64+c 3136]
#define W2PL 18432u
#define W3PL 36864u
#define W4PL 802816u
#define ZOFF 3432448u      // 2560 zero elems (invalid-tap A source)
#define WPTOT2 3435008u

__device__ __forceinline__ int imin(int a, int b) { return a < b ? a : b; }

__device__ __forceinline__ void bsplit(float v, ushort_t& h, ushort_t& lo) {
  union { float f; unsigned u; } a; a.f = v;
  unsigned uh = (a.u + 0x7fffu + ((a.u >> 16) & 1u)) & 0xffff0000u;
  h = (ushort_t)(uh >> 16);
  union { unsigned u; float f; } b; b.u = uh;
  float r = v - b.f;
  union { float f; unsigned u; } c; c.f = r;
  lo = (ushort_t)((c.u + 0x7fffu + ((c.u >> 16) & 1u)) >> 16);
}

__device__ __forceinline__ float bjoin(ushort_t h, ushort_t l) {
  union { unsigned u; float f; } a, b;
  a.u = ((unsigned)h) << 16; b.u = ((unsigned)l) << 16;
  return a.f + b.f;
}

// one K=32 MFMA step for NSUB n-subtiles from GLOBAL B (used by k_hgemm)
template <int NSUB>
__device__ __forceinline__ void kstep(f4_t* acc, const ushort_t* ap, size_t apl,
                                      const ushort_t* bp, size_t bpl, int bstride) {
  bf8_t ah = *(const bf8_t*)ap;
  bf8_t al = *(const bf8_t*)(ap + apl);
#pragma unroll
  for (int j = 0; j < NSUB; ++j) {
    const ushort_t* b = bp + (size_t)j * 16 * bstride;
    bf8_t bh = *(const bf8_t*)b;
    bf8_t bl = *(const bf8_t*)(b + bpl);
    acc[j] = MFMA16(ah, bh, acc[j], 0, 0, 0);
    acc[j] = MFMA16(ah, bl, acc[j], 0, 0, 0);
    acc[j] = MFMA16(al, bh, acc[j], 0, 0, 0);
  }
}

__global__ void k_fill0(float* p, unsigned n) {
  for (unsigned i = blockIdx.x * blockDim.x + threadIdx.x; i < n;
       i += gridDim.x * blockDim.x)
    p[i] = 0.f;
}

__global__ void k_pack2(const float* __restrict__ w2, ushort_t* __restrict__ WP) {
  int idx = blockIdx.x * blockDim.x + threadIdx.x;
  if (idx >= 18432) return;
  int co = idx / 288, rem = idx % 288, ci = rem / 9, t = rem % 9;
  ushort_t h, l; bsplit(w2[idx], h, l);
  unsigned f = W2F_OFF + t * 2048 + co * 32 + ci;
  unsigned b = W2B_OFF + t * 2048 + ci * 64 + co;
  WP[f] = h; WP[f + W2PL] = l;
  WP[b] = h; WP[b + W2PL] = l;
}

__global__ void k_pack3(const float* __restrict__ w3, ushort_t* __restrict__ WP) {
  int idx = blockIdx.x * blockDim.x + threadIdx.x;
  if (idx >= 36864) return;
  int co = idx / 576, rem = idx % 576, ci = rem / 9, t = rem % 9;
  ushort_t h, l; bsplit(w3[idx], h, l);
  unsigned f = W3F_OFF + t * 4096 + co * 64 + ci;
  unsigned b = W3B_OFF + t * 4096 + ci * 64 + co;
  WP[f] = h; WP[f + W3PL] = l;
  WP[b] = h; WP[b + W3PL] = l;
}

__global__ void k_pack4(const float* __restrict__ w4, ushort_t* __restrict__ WP) {
  int idx = blockIdx.x * blockDim.x + threadIdx.x;
  if (idx >= 802816) return;
  int o = idx / 3136, kk = idx % 3136, c = kk / 49, p = kk % 49;
  ushort_t h, l; bsplit(w4[idx], h, l);
  unsigned a = W4P_OFF + p * 16384 + c * 256 + o;
  unsigned b = W4Q_OFF + o * 3136 + p * 64 + c;
  WP[a] = h; WP[a + W4PL] = l;
  WP[b] = h; WP[b + W4PL] = l;
}

// u1[q][n][c]: conv1 of basis vector n (n==784 -> b1, pads 0), split bf16
__global__ void k_u1b(ushort_t* __restrict__ G, const float* __restrict__ w1,
                      const float* __restrict__ b1) {
  unsigned idx = blockIdx.x * blockDim.x + threadIdx.x;
  if (idx >= GPL) return;
  int q = idx / 26624, rem = idx % 26624, n = rem / 32, c = rem % 32;
  int oy = q / 14, ox = q % 14;
  float v = 0.f;
  if (n < 784) {
    int py = n / 28, px = n % 28;
    int ky = py - (2 * oy - 1), kx = px - (2 * ox - 1);
    if (ky >= 0 && ky < 3 && kx >= 0 && kx < 3) v = w1[c * 9 + ky * 3 + kx];
  } else if (n == 784) {
    v = b1[c];
  }
  ushort_t h, l; bsplit(v, h, l);
  G[idx] = h; G[idx + GPL] = l;
}

// P1 = 0.5*s1_final - u1
__global__ void k_p1(ushort_t* __restrict__ D, const ushort_t* __restrict__ S,
                     const ushort_t* __restrict__ G) {
  unsigned g8 = (blockIdx.x * blockDim.x + threadIdx.x) * 8;
  if (g8 >= GPL) return;
  size_t off = (size_t)R1G + g8;
  bf8_t oh = *(const bf8_t*)&S[off], ol = *(const bf8_t*)&S[off + SELG];
  bf8_t gh = *(const bf8_t*)&G[g8], gl = *(const bf8_t*)&G[g8 + GPL];
  bf8_t rh, rl;
#pragma unroll
  for (int e = 0; e < 8; ++e) {
    float v = 0.5f * bjoin((ushort_t)oh[e], (ushort_t)ol[e]) -
              bjoin((ushort_t)gh[e], (ushort_t)gl[e]);
    ushort_t h, l; bsplit(v, h, l);
    rh[e] = (short)h; rl[e] = (short)l;
  }
  *(bf8_t*)&D[off] = rh;
  *(bf8_t*)&D[off + SELG] = rl;
}

// ---- chunk descriptors for the pipelined mega kernel ----
struct Ent { unsigned eh, el; int b; int ars, brs; };

__device__ __forceinline__ Ent entry(int role, int e, int p, int mt, int post) {
  Ent E;
  if (role == 3) {
    E.eh = W4Q_OFF + ((unsigned)mt * 64u) * 3136u + (unsigned)e * 32u;
    E.el = E.eh + W4PL;
    E.b = R3G + (e >> 1) * 53248 + (e & 1) * 32;
    E.ars = 3136; E.brs = 64;
  } else if (role == 2) {
    int y = p / 7, x = p % 7;
    if (e < 18) {
      int t = e >> 1, sub = e & 1, ky = t / 3, kx = t % 3;
      int iy = y - 1 + ky, ix = x - 1 + kx;
      bool v = (iy >= 0 && iy < 7 && ix >= 0 && ix < 7);
      E.eh = v ? (W3F_OFF + t * 4096u + sub * 32u) : ZOFF;
      E.el = v ? (E.eh + W3PL) : ZOFF;
      E.b = R2G + (iy * 7 + ix) * 53248 + sub * 32;
      E.ars = v ? 64 : 32; E.brs = 64;
    } else {
      int s = e - 18;
      E.eh = W4P_OFF + (unsigned)p * 16384u + s * 32u;
      E.el = E.eh + W4PL;
      E.b = R4G + s * 32;
      E.ars = 256; E.brs = 256;
    }
  } else if (role == 1) {
    int y = p / 7, x = p % 7;
    if (e < 9) {
      int ky = e / 3, kx = e % 3;
      int iy = 2 * y - 1 + ky, ix = 2 * x - 1 + kx;
      bool v = (iy >= 0 && iy < 14 && ix >= 0 && ix < 14);
      E.eh = v ? (W2F_OFF + e * 2048u) : ZOFF;
      E.el = v ? (E.eh + W2PL) : ZOFF;
      E.b = R1G + (iy * 14 + ix) * 26624;
      E.ars = 32; E.brs = 32;
    } else if (e < 27 && !post) {
      int u = e - 9, t = u >> 1, sub = u & 1, ky = t / 3, kx = t % 3;
      int ty = y + 1 - ky, tx = x + 1 - kx;
      bool v = (ty >= 0 && ty < 7 && tx >= 0 && tx < 7);
      E.eh = v ? (W3B_OFF + t * 4096u + sub * 32u) : ZOFF;
      E.el = v ? (E.eh + W3PL) : ZOFF;
      E.b = R3G + (ty * 7 + tx) * 53248 + sub * 32;
      E.ars = v ? 64 : 32; E.brs = 64;
    } else {  // pad entry (zero A)
      E.eh = ZOFF; E.el = ZOFF; E.b = R4G; E.ars = 32; E.brs = 256;
    }
  } else {  // role 0: s1 update, conv2^T (parity taps)
    int y = p / 14, x = p % 14;
    int tj = e >> 1, sub = e & 1, jy = tj >> 1, jx = tj & 1;
    int ky = (y & 1) ? 2 * jy : 1;
    int kx = (x & 1) ? 2 * jx : 1;
    bool py_ = (y & 1) || (jy == 0);
    bool px_ = (x & 1) || (jx == 0);
    int oy = (y + 1 - ky) >> 1, ox = (x + 1 - kx) >> 1;
    bool v = py_ && px_ && oy >= 0 && oy < 7 && ox >= 0 && ox < 7;
    int t = ky * 3 + kx;
    E.eh = v ? (W2B_OFF + t * 2048u + sub * 32u) : ZOFF;
    E.el = v ? (E.eh + W2PL) : ZOFF;
    E.b = R2G + (oy * 7 + ox) * 53248 + sub * 32;
    E.ars = v ? 64 : 32; E.brs = 64;
  }
  return E;
}

// pipelined main loop: double-buffered LDS B-tiles (64n x 32k, 80B rows),
// A-frags issued first (vmcnt(4) releases MFMA while stage loads stay pending),
// stage(j+1) global->reg during MFMA(j), ds_write late, ONE barrier per chunk.
template <int NSUB>
__device__ __forceinline__ void mloop(int role, int post, int p, int mt, int n0,
                                      int NC2, int mrow, int nbase,
                                      const ushort_t* __restrict__ S,
                                      const ushort_t* __restrict__ WP,
                                      ushort_t* __restrict__ SB, f4_t (&acc)[4]) {
  const int tid = threadIdx.x;
  const int l = tid & 63;
  const int lm = l & 15, koff = (l >> 4) * 8;
  const int sn = tid >> 2, sc = (tid & 3) * 8;
  Ent E0 = entry(role, 0, p, mt, post);
  Ent E1 = entry(role, 1, p, mt, post);
  bf8_t s0h, s0l, s1h, s1l;
  s0h = *(const bf8_t*)(S + E0.b + (n0 + sn) * E0.brs + sc);
  s0l = *(const bf8_t*)(S + SELG + E0.b + (n0 + sn) * E0.brs + sc);
  s1h = *(const bf8_t*)(S + E1.b + (n0 + sn) * E1.brs + sc);
  s1l = *(const bf8_t*)(S + SELG + E1.b + (n0 + sn) * E1.brs + sc);
  {
    int wb = sn * 40 + sc;
    *(bf8_t*)&SB[wb] = s0h;          *(bf8_t*)&SB[wb + 2560] = s0l;
    *(bf8_t*)&SB[wb + 5120] = s1h;   *(bf8_t*)&SB[wb + 7680] = s1l;
  }
  __syncthreads();
  for (int j = 0; j < NC2; ++j) {
    // A fragments for current chunk (oldest vmem this iteration)
    int mo0 = mrow * E0.ars + koff;
    bf8_t ah0 = *(const bf8_t*)(WP + E0.eh + mo0);
    bf8_t al0 = *(const bf8_t*)(WP + E0.el + mo0);
    int mo1 = mrow * E1.ars + koff;
    bf8_t ah1 = *(const bf8_t*)(WP + E1.eh + mo1);
    bf8_t al1 = *(const bf8_t*)(WP + E1.el + mo1);
    bool more = (j + 1 < NC2);
    if (more) {
      E0 = entry(role, 2 * j + 2, p, mt, post);
      E1 = entry(role, 2 * j + 3, p, mt, post);
      s0h = *(const bf8_t*)(S + E0.b + (n0 + sn) * E0.brs + sc);
      s0l = *(const bf8_t*)(S + SELG + E0.b + (n0 + sn) * E0.brs + sc);
      s1h = *(const bf8_t*)(S + E1.b + (n0 + sn) * E1.brs + sc);
      s1l = *(const bf8_t*)(S + SELG + E1.b + (n0 + sn) * E1.brs + sc);
    }
    const ushort_t* Bb = SB + (j & 1) * 10240;
#pragma unroll
    for (int jn = 0; jn < NSUB; ++jn) {
      int lo = (nbase + jn * 16 + lm) * 40 + koff;
      bf8_t bh = *(const bf8_t*)&Bb[lo];
      bf8_t bl = *(const bf8_t*)&Bb[lo + 2560];
      acc[jn] = MFMA16(ah0, bh, acc[jn], 0, 0, 0);
      acc[jn] = MFMA16(ah0, bl, acc[jn], 0, 0, 0);
      acc[jn] = MFMA16(al0, bh, acc[jn], 0, 0, 0);
    }
#pragma unroll
    for (int jn = 0; jn < NSUB; ++jn) {
      int lo = 5120 + (nbase + jn * 16 + lm) * 40 + koff;
      bf8_t bh = *(const bf8_t*)&Bb[lo];
      bf8_t bl = *(const bf8_t*)&Bb[lo + 2560];
      acc[jn] = MFMA16(ah1, bh, acc[jn], 0, 0, 0);
      acc[jn] = MFMA16(ah1, bl, acc[jn], 0, 0, 0);
      acc[jn] = MFMA16(al1, bh, acc[jn], 0, 0, 0);
    }
    if (more) {
      ushort_t* Wb = SB + ((j + 1) & 1) * 10240;
      int wb = sn * 40 + sc;
      *(bf8_t*)&Wb[wb] = s0h;          *(bf8_t*)&Wb[wb + 2560] = s0l;
      *(bf8_t*)&Wb[wb + 5120] = s1h;   *(bf8_t*)&Wb[wb + 7680] = s1l;
    }
    __syncthreads();
  }
}

// epilogue for C=64 state regions (s2/s3): LDS f32 tile [n 64][64] -> hi/lo out
__device__ __forceinline__ void epi_c64(ushort_t* __restrict__ D,
                                        const ushort_t* __restrict__ S,
                                        const float* __restrict__ Lt, int rbase,
                                        int pos, int n0, const float* __restrict__ bias,
                                        int post) {
  int tid = threadIdx.x;
  int nl = tid >> 2, cq = (tid & 3) * 16;
  int n = n0 + nl;
  size_t off = (size_t)rbase + (size_t)pos * 53248 + (size_t)n * 64 + cq;
  const float* lp = Lt + nl * 65 + cq;
#pragma unroll
  for (int half = 0; half < 2; ++half) {
    size_t o8 = off + half * 8;
    bf8_t oh = *(const bf8_t*)&S[o8], ol = *(const bf8_t*)&S[o8 + SELG];
    bf8_t rh, rl;
#pragma unroll
    for (int e = 0; e < 8; ++e) {
      float v = lp[half * 8 + e];
      if (n == 784) v += bias[cq + half * 8 + e];
      float old = bjoin((ushort_t)oh[e], (ushort_t)ol[e]);
      float nv = post ? 0.5f * old - v : 0.5f * old + 0.5f * v;
      ushort_t h, l; bsplit(nv, h, l);
      rh[e] = (short)h; rl[e] = (short)l;
    }
    *(bf8_t*)&D[o8] = rh;
    *(bf8_t*)&D[o8 + SELG] = rl;
  }
}

// mega kernel: iter blocks [role3 52][role2 637][role1 637][role0 2548]
// post blocks [role3 52][role2 637][role1 637]
__global__ __launch_bounds__(256) void k_mega(
    const ushort_t* __restrict__ S, ushort_t* __restrict__ D,
    const ushort_t* __restrict__ G, const ushort_t* __restrict__ WP,
    const float* __restrict__ b2, const float* __restrict__ b3,
    const float* __restrict__ b4, int post) {
  __shared__ __align__(16) ushort_t SB[20480];
  float* Lt = (float*)SB;
  const int tid = threadIdx.x;
  const int l = tid & 63, w = tid >> 6;
  const int lm = l & 15, lk = l >> 4;
  int b = blockIdx.x;
  int role, rb;
  if (b < 52) { role = 3; rb = b; }
  else if (b < 689) { role = 2; rb = b - 52; }
  else if (b < 1326) { role = 1; rb = b - 689; }
  else { role = 0; rb = b - 1326; }

  f4_t acc[4] = {{0.f,0.f,0.f,0.f},{0.f,0.f,0.f,0.f},{0.f,0.f,0.f,0.f},{0.f,0.f,0.f,0.f}};
  int ntile = rb % 13, pq = rb / 13;
  int n0 = ntile * 64;

  if (role == 0) {
    mloop<2>(0, post, pq, 0, n0, 4, (w & 1) * 16 + lm, (w >> 1) * 32, S, WP, SB, acc);
  } else {
    int NC2 = (role == 3) ? 49 : (role == 2) ? (post ? 9 : 13) : (post ? 5 : 14);
    mloop<4>(role, post, pq, pq, n0, NC2, w * 16 + lm, 0, S, WP, SB, acc);
  }

  if (role == 0) {
#pragma unroll
    for (int jn = 0; jn < 2; ++jn)
#pragma unroll
      for (int r = 0; r < 4; ++r)
        Lt[((w >> 1) * 32 + 16 * jn + lm) * 33 + (w & 1) * 16 + lk * 4 + r] = acc[jn][r];
  } else {
#pragma unroll
    for (int jn = 0; jn < 4; ++jn)
#pragma unroll
      for (int r = 0; r < 4; ++r)
        Lt[(16 * jn + lm) * 65 + w * 16 + lk * 4 + r] = acc[jn][r];
  }
  __syncthreads();

  if (role == 0) {
    int nl = tid >> 2, cq = (tid & 3) * 8;
    int n = n0 + nl;
    size_t off = (size_t)R1G + (size_t)pq * 26624 + (size_t)n * 32 + cq;
    size_t goff = (size_t)pq * 26624 + (size_t)n * 32 + cq;
    bf8_t oh = *(const bf8_t*)&S[off], ol = *(const bf8_t*)&S[off + SELG];
    bf8_t gh = *(const bf8_t*)&G[goff], gl = *(const bf8_t*)&G[goff + GPL];
    const float* lp = Lt + nl * 33 + cq;
    bf8_t rh, rl;
#pragma unroll
    for (int e = 0; e < 8; ++e) {
      float old = bjoin((ushort_t)oh[e], (ushort_t)ol[e]);
      float u = bjoin((ushort_t)gh[e], (ushort_t)gl[e]);
      float nv = 0.5f * old + 0.5f * (lp[e] + u);
      ushort_t h, lo2; bsplit(nv, h, lo2);
      rh[e] = (short)h; rl[e] = (short)lo2;
    }
    *(bf8_t*)&D[off] = rh;
    *(bf8_t*)&D[off + SELG] = rl;
  } else if (role == 1) {
    epi_c64(D, S, Lt, R2G, pq, n0, b2, post);
  } else if (role == 2) {
    epi_c64(D, S, Lt, R3G, pq, n0, b3, post);
  } else {
    int nl = tid >> 2, cq = (tid & 3) * 16;
    int n = n0 + nl, mt = pq;
    size_t off = (size_t)R4G + (size_t)n * 256 + mt * 64 + cq;
    const float* lp = Lt + nl * 65 + cq;
#pragma unroll
    for (int half = 0; half < 2; ++half) {
      size_t o8 = off + half * 8;
      bf8_t oh = *(const bf8_t*)&S[o8], ol = *(const bf8_t*)&S[o8 + SELG];
      bf8_t rh, rl;
#pragma unroll
      for (int e = 0; e < 8; ++e) {
        float v = lp[half * 8 + e];
        if (n == 784) v += b4[mt * 64 + cq + half * 8 + e];
        float old = bjoin((ushort_t)oh[e], (ushort_t)ol[e]);
        float nv = post ? 0.5f * old - v : 0.5f * old + 0.5f * v;
        ushort_t h, l2; bsplit(nv, h, l2);
        rh[e] = (short)h; rl[e] = (short)l2;
      }
      *(bf8_t*)&D[o8] = rh;
      *(bf8_t*)&D[o8 + SELG] = rl;
    }
  }
}

// H[j][k] = sum_d P[d][j] S[d][k] — MFMA over channel-minor layout, split-K 4
__device__ __forceinline__ void hstep(int s, size_t& base, int& C, int& c0) {
  if (s < 196) { base = R1G + (size_t)s * 26624; C = 32; c0 = 0; }
  else if (s < 294) { int u = s - 196; base = R2G + (size_t)(u >> 1) * 53248; C = 64; c0 = (u & 1) * 32; }
  else if (s < 392) { int u = s - 294; base = R3G + (size_t)(u >> 1) * 53248; C = 64; c0 = (u & 1) * 32; }
  else { base = R4G; C = 256; c0 = (s - 392) * 32; }
}

__global__ __launch_bounds__(256) void k_hgemm(float* __restrict__ Hp,
                                               const ushort_t* __restrict__ P,
                                               const ushort_t* __restrict__ S) {
  int tid = threadIdx.x, l = tid & 63, w = tid >> 6;
  int m0 = blockIdx.y * 64 + w * 16, n0 = blockIdx.x * 64;
  int z = blockIdx.z;
  int koff = (l >> 4) * 8;
  int s0 = z * 100, s1e = (z + 1) * 100;
  f4_t acc[4] = {{0.f,0.f,0.f,0.f},{0.f,0.f,0.f,0.f},{0.f,0.f,0.f,0.f},{0.f,0.f,0.f,0.f}};
  for (int s = s0; s < s1e; ++s) {
    size_t base; int C, c0;
    hstep(s, base, C, c0);
    const ushort_t* A = P + base + (size_t)(m0 + (l & 15)) * C + c0 + koff;
    const ushort_t* B = S + base + (size_t)(n0 + (l & 15)) * C + c0 + koff;
    kstep<4>(acc, A, SELG, B, SELG, C);
  }
#pragma unroll
  for (int j = 0; j < 4; ++j)
#pragma unroll
    for (int r = 0; r < 4; ++r)
      Hp[((size_t)z * NBn + m0 + (l >> 4) * 4 + r) * NBn + n0 + 16 * j + (l & 15)] =
          acc[j][r];
}

__global__ void k_combine(float* __restrict__ C, int ldc, const float* __restrict__ part,
                          int M, int N, int KS, float alpha, float beta,
                          const float* __restrict__ P0, int ldp,
                          const float* __restrict__ biasM, int bias_col) {
  int total = M * N;
  for (int idx = blockIdx.x * blockDim.x + threadIdx.x; idx < total;
       idx += gridDim.x * blockDim.x) {
    int m = idx / N, n = idx % N;
    float s = 0.f;
    for (int zz = 0; zz < KS; ++zz) s += part[((size_t)zz * M + m) * N + n];
    if (biasM && n == bias_col) s += biasM[m];
    s *= alpha;
    if (P0) s += beta * P0[(size_t)m * ldp + n];
    C[(size_t)m * ldc + n] = s;
  }
}

// fp32 register-blocked GEMM: C = alpha*(A*B + biasN) + beta*P0
__global__ __launch_bounds__(256) void gemm64(
    float* __restrict__ C, int ldc, const float* __restrict__ A, int lda,
    const float* __restrict__ B, int ldb, int M, int N, int K, float alpha,
    float beta, const float* __restrict__ P0, int ldp,
    const float* __restrict__ biasN) {
  __shared__ float As[32][68];
  __shared__ float Bs[32][68];
  const int tid = threadIdx.x;
  const int tx = tid & 15, ty = tid >> 4;
  const int m0 = blockIdx.y * 64, n0 = blockIdx.x * 64;
  const int lk = tid >> 3, lm4 = (tid & 7) * 8;
  const int lmn = tid >> 2, lkq = (tid & 3) * 8;
  float acc[4][4] = {};
  for (int k0 = 0; k0 < K; k0 += 32) {
    __syncthreads();
    {
      int gm = m0 + lmn;
#pragma unroll
      for (int h = 0; h < 2; ++h) {
        int gk = k0 + lkq + h * 4;
        float4 v = {0.f, 0.f, 0.f, 0.f};
        if (gm < M && gk + 4 <= K) v = *(const float4*)&A[(size_t)gm * lda + gk];
        As[lkq + h * 4 + 0][lmn] = v.x;
        As[lkq + h * 4 + 1][lmn] = v.y;
        As[lkq + h * 4 + 2][lmn] = v.z;
        As[lkq + h * 4 + 3][lmn] = v.w;
      }
    }
    {
      int gk = k0 + lk, gn = n0 + lm4;
#pragma unroll
      for (int h = 0; h < 2; ++h) {
        float4 v = {0.f, 0.f, 0.f, 0.f};
        if (gk < K && gn + h * 4 + 4 <= N)
          v = *(const float4*)&B[(size_t)gk * ldb + gn + h * 4];
        *(float4*)&Bs[lk][lm4 + h * 4] = v;
      }
    }
    __syncthreads();
#pragma unroll 16
    for (int kk = 0; kk < 32; ++kk) {
      float4 a_ = *(const float4*)&As[kk][ty * 4];
      float4 b_ = *(const float4*)&Bs[kk][tx * 4];
      acc[0][0] += a_.x * b_.x; acc[0][1] += a_.x * b_.y;
      acc[0][2] += a_.x * b_.z; acc[0][3] += a_.x * b_.w;
      acc[1][0] += a_.y * b_.x; acc[1][1] += a_.y * b_.y;
      acc[1][2] += a_.y * b_.z; acc[1][3] += a_.y * b_.w;
      acc[2][0] += a_.z * b_.x; acc[2][1] += a_.z * b_.y;
      acc[2][2] += a_.z * b_.z; acc[2][3] += a_.z * b_.w;
      acc[3][0] += a_.w * b_.x; acc[3][1] += a_.w * b_.y;
      acc[3][2] += a_.w * b_.z; acc[3][3] += a_.w * b_.w;
    }
  }
#pragma unroll
  for (int i = 0; i < 4; ++i) {
    int m = m0 + ty * 4 + i, n = n0 + tx * 4;
    if (m >= M || n + 4 > N) continue;
    float4 v;
    float* vp = (float*)&v;
#pragma unroll
    for (int j = 0; j < 4; ++j) {
      float s = acc[i][j];
      if (biasN) s += biasN[n + j];
      s *= alpha;
      if (P0) s += beta * P0[(size_t)m * ldp + n + j];
      vp[j] = s;
    }
    *(float4*)&C[(size_t)m * ldc + n] = v;
  }
}

// out[i] = 0.5||x_i||^2 - vb.x_i + sum_{j<784} x_ij Y[i,j] + Y[i,784]
__global__ void k_out(float* __restrict__ out, const float* __restrict__ x,
                      const float* __restrict__ vb, const float* __restrict__ Y, int Bn) {
  int wave = threadIdx.x >> 6, lane = threadIdx.x & 63;
  int i = blockIdx.x * 4 + wave;
  if (i >= Bn) return;
  const float* xi = x + (size_t)i * 784;
  const float* yi = Y + (size_t)i * NBn;
  float s = 0.f;
  for (int j = lane; j < 784; j += 64) {
    float xv = xi[j];
    s += xv * (0.5f * xv - vb[j] + yi[j]);
  }
  for (int off = 32; off; off >>= 1) s += __shfl_down(s, off);
  if (lane == 0) out[i] = s + yi[784];
}

extern "C" void kernel_launch(void* const* d_in, const int* in_sizes, int n_in, void* d_out,
                              int out_size, void* d_ws, size_t ws_size, hipStream_t stream) {
  const float* x  = (const float*)d_in[0];
  const float* vb = (const float*)d_in[1];
  const float* w1 = (const float*)d_in[2];
  const float* b1 = (const float*)d_in[3];
  const float* w2 = (const float*)d_in[4];
  const float* b2 = (const float*)d_in[5];
  const float* w3 = (const float*)d_in[6];
  const float* b3 = (const float*)d_in[7];
  const float* w4 = (const float*)d_in[8];
  const float* b4 = (const float*)d_in[9];
  int Bn = in_sizes[0] / 784;
  float* out = (float*)d_out;

  ushort_t* Sa = (ushort_t*)d_ws;                    // 2*SELG
  ushort_t* Sb = Sa + (size_t)2 * SELG;              // 2*SELG
  ushort_t* G  = Sb + (size_t)2 * SELG;              // 2*GPL (aliased by Ybuf at end)
  ushort_t* WP = G + (size_t)2 * GPL;                // WPTOT2
  float* Hpart = (float*)(WP + WPTOT2);              // 4*832*832 f32
  float* Hmat  = Hpart + (size_t)4 * NBn * NBn;      // 832*832 f32
  float* Ybuf  = (float*)G;                          // Bn*832 f32 (G dead by then)

  const int TB = 256;
  k_fill0<<<2048, TB, 0, stream>>>((float*)Sa, SELG);
  k_fill0<<<2048, TB, 0, stream>>>((float*)Sb, SELG);
  k_fill0<<<2, TB, 0, stream>>>((float*)(WP + ZOFF), 1280);
  k_pack2<<<72, TB, 0, stream>>>(w2, WP);
  k_pack3<<<144, TB, 0, stream>>>(w3, WP);
  k_pack4<<<3136, TB, 0, stream>>>(w4, WP);
  k_u1b<<<20384, TB, 0, stream>>>(G, w1, b1);

  ushort_t* cur = Sa;
  ushort_t* nxt = Sb;
  for (int it = 0; it < NITER; ++it) {
    k_mega<<<3874, TB, 0, stream>>>(cur, nxt, G, WP, b2, b3, b4, 0);
    ushort_t* t = cur; cur = nxt; nxt = t;
  }

  // post fields P into nxt
  k_p1<<<2548, TB, 0, stream>>>(nxt, cur, G);
  k_mega<<<1326, TB, 0, stream>>>(cur, nxt, G, WP, b2, b3, b4, 1);

  // H = P' S (split-K 4) -> Hmat
  k_hgemm<<<dim3(13, 13, 4), TB, 0, stream>>>(Hpart, nxt, cur);
  k_combine<<<2048, TB, 0, stream>>>(Hmat, NBn, Hpart, NBn, NBn, 4, 1.f, 0.f, nullptr, 0,
                                     nullptr, -1);

  // Y = x~ * H (fp32), then out
  gemm64<<<dim3(13, (Bn + 63) / 64), TB, 0, stream>>>(
      Ybuf, NBn, x, 784, Hmat, NBn, Bn, NBn, 784, 1.f, 0.f, nullptr, 0,
      Hmat + (size_t)784 * NBn);
  k_out<<<(Bn + 3) / 4, TB, 0, stream>>>(out, x, vb, Ybuf, Bn);
}

// Round 5
// 3804.133 us; speedup vs baseline: 28.1035x; 1.2630x over previous
//
#include <hip/hip_runtime.h>
#include <cstddef>

// Basis-propagation; iteration in PURE bf16 (errors second-order suppressed at
// the energy minimum), post-fields/H/Y in bf16 hi/lo (2^-17) for exact E(S~).
// State S[pos][n][c] channel-minor, single plane during iteration, guard bands
// make every conv tap address-safe; invalid taps use a zero-weight block.

typedef unsigned short ushort_t;
typedef __attribute__((ext_vector_type(8))) short bf8_t;   // 8 bf16
typedef __attribute__((ext_vector_type(4))) float f4_t;

#define MFMA16 __builtin_amdgcn_mfma_f32_16x16x32_bf16

#define NBn 832
#define NITER 50
#define GPL 5218304u       // u1/G plane size (196*26624)

// state plane geometry (elems), with guards:
// [g1pre 15*26624][s1 196*26624][g2pre 8*53248][s2 49*53248][g2post 15*53248]
// [g3pre 8*53248][s3 49*53248][g3post 8*53248][s4 832*256]
#define SELG 13125632u
#define R1G 399360
#define R2G 6043648
#define R3G 9877504
#define R4G 12912640

// packed weights (elems; each matrix = [hi plane][lo plane])
#define W2F_OFF 0u         // [t][co 64][ci 32]
#define W2B_OFF 36864u     // [t][ci 32][co 64]
#define W3F_OFF 73728u     // [t][co 64][ci 64]
#define W3B_OFF 147456u    // [t][ci 64][co 64]
#define W4P_OFF 221184u    // [p 49][c 64][o 256]
#define W4Q_OFF 1826816u   // [o 256][p*64+c 3136]
#define W2PL 18432u
#define W3PL 36864u
#define W4PL 802816u
#define ZOFF 3432448u      // 2560 zero elems (invalid-tap A source)
#define WPTOT2 3435008u

__device__ __forceinline__ void bsplit(float v, ushort_t& h, ushort_t& lo) {
  union { float f; unsigned u; } a; a.f = v;
  unsigned uh = (a.u + 0x7fffu + ((a.u >> 16) & 1u)) & 0xffff0000u;
  h = (ushort_t)(uh >> 16);
  union { unsigned u; float f; } b; b.u = uh;
  float r = v - b.f;
  union { float f; unsigned u; } c; c.f = r;
  lo = (ushort_t)((c.u + 0x7fffu + ((c.u >> 16) & 1u)) >> 16);
}

__device__ __forceinline__ ushort_t bround(float v) {
  union { float f; unsigned u; } a; a.f = v;
  return (ushort_t)((a.u + 0x7fffu + ((a.u >> 16) & 1u)) >> 16);
}

__device__ __forceinline__ float b2f(ushort_t h) {
  union { unsigned u; float f; } a; a.u = ((unsigned)h) << 16;
  return a.f;
}

__device__ __forceinline__ float bjoin(ushort_t h, ushort_t l) {
  return b2f(h) + b2f(l);
}

__global__ void k_fill0(float* p, unsigned n) {
  for (unsigned i = blockIdx.x * blockDim.x + threadIdx.x; i < n;
       i += gridDim.x * blockDim.x)
    p[i] = 0.f;
}

__global__ void k_pack2(const float* __restrict__ w2, ushort_t* __restrict__ WP) {
  int idx = blockIdx.x * blockDim.x + threadIdx.x;
  if (idx >= 18432) return;
  int co = idx / 288, rem = idx % 288, ci = rem / 9, t = rem % 9;
  ushort_t h, l; bsplit(w2[idx], h, l);
  unsigned f = W2F_OFF + t * 2048 + co * 32 + ci;
  unsigned b = W2B_OFF + t * 2048 + ci * 64 + co;
  WP[f] = h; WP[f + W2PL] = l;
  WP[b] = h; WP[b + W2PL] = l;
}

__global__ void k_pack3(const float* __restrict__ w3, ushort_t* __restrict__ WP) {
  int idx = blockIdx.x * blockDim.x + threadIdx.x;
  if (idx >= 36864) return;
  int co = idx / 576, rem = idx % 576, ci = rem / 9, t = rem % 9;
  ushort_t h, l; bsplit(w3[idx], h, l);
  unsigned f = W3F_OFF + t * 4096 + co * 64 + ci;
  unsigned b = W3B_OFF + t * 4096 + ci * 64 + co;
  WP[f] = h; WP[f + W3PL] = l;
  WP[b] = h; WP[b + W3PL] = l;
}

__global__ void k_pack4(const float* __restrict__ w4, ushort_t* __restrict__ WP) {
  int idx = blockIdx.x * blockDim.x + threadIdx.x;
  if (idx >= 802816) return;
  int o = idx / 3136, kk = idx % 3136, c = kk / 49, p = kk % 49;
  ushort_t h, l; bsplit(w4[idx], h, l);
  unsigned a = W4P_OFF + p * 16384 + c * 256 + o;
  unsigned b = W4Q_OFF + o * 3136 + p * 64 + c;
  WP[a] = h; WP[a + W4PL] = l;
  WP[b] = h; WP[b + W4PL] = l;
}

// u1[q][n][c]: conv1 of basis vector n (n==784 -> b1, pads 0), split bf16
__global__ void k_u1b(ushort_t* __restrict__ G, const float* __restrict__ w1,
                      const float* __restrict__ b1) {
  unsigned idx = blockIdx.x * blockDim.x + threadIdx.x;
  if (idx >= GPL) return;
  int q = idx / 26624, rem = idx % 26624, n = rem / 32, c = rem % 32;
  int oy = q / 14, ox = q % 14;
  float v = 0.f;
  if (n < 784) {
    int py = n / 28, px = n % 28;
    int ky = py - (2 * oy - 1), kx = px - (2 * ox - 1);
    if (ky >= 0 && ky < 3 && kx >= 0 && kx < 3) v = w1[c * 9 + ky * 3 + kx];
  } else if (n == 784) {
    v = b1[c];
  }
  ushort_t h, l; bsplit(v, h, l);
  G[idx] = h; G[idx + GPL] = l;
}

// P1 = 0.5*s1_final - u1  (hi/lo into Pb)
__global__ void k_p1(ushort_t* __restrict__ D, const ushort_t* __restrict__ S,
                     const ushort_t* __restrict__ G) {
  unsigned g8 = (blockIdx.x * blockDim.x + threadIdx.x) * 8;
  if (g8 >= GPL) return;
  size_t off = (size_t)R1G + g8;
  bf8_t oh = *(const bf8_t*)&S[off];
  bf8_t gh = *(const bf8_t*)&G[g8], gl = *(const bf8_t*)&G[g8 + GPL];
  bf8_t rh, rl;
#pragma unroll
  for (int e = 0; e < 8; ++e) {
    float v = 0.5f * b2f((ushort_t)oh[e]) -
              bjoin((ushort_t)gh[e], (ushort_t)gl[e]);
    ushort_t h, l; bsplit(v, h, l);
    rh[e] = (short)h; rl[e] = (short)l;
  }
  *(bf8_t*)&D[off] = rh;
  *(bf8_t*)&D[off + SELG] = rl;
}

// ---- chunk descriptors ----
struct Ent { unsigned eh, el; int b; int ars, brs; };

__device__ __forceinline__ Ent entry(int role, int e, int p, int mt, int post) {
  Ent E;
  if (role == 3) {
    E.eh = W4Q_OFF + ((unsigned)mt * 64u) * 3136u + (unsigned)e * 32u;
    E.el = E.eh + W4PL;
    E.b = R3G + (e >> 1) * 53248 + (e & 1) * 32;
    E.ars = 3136; E.brs = 64;
  } else if (role == 2) {
    int y = p / 7, x = p % 7;
    if (e < 18) {
      int t = e >> 1, sub = e & 1, ky = t / 3, kx = t % 3;
      int iy = y - 1 + ky, ix = x - 1 + kx;
      bool v = (iy >= 0 && iy < 7 && ix >= 0 && ix < 7);
      E.eh = v ? (W3F_OFF + t * 4096u + sub * 32u) : ZOFF;
      E.el = v ? (E.eh + W3PL) : ZOFF;
      E.b = R2G + (iy * 7 + ix) * 53248 + sub * 32;
      E.ars = v ? 64 : 32; E.brs = 64;
    } else {
      int s = e - 18;
      E.eh = W4P_OFF + (unsigned)p * 16384u + s * 32u;
      E.el = E.eh + W4PL;
      E.b = R4G + s * 32;
      E.ars = 256; E.brs = 256;
    }
  } else if (role == 1) {
    int y = p / 7, x = p % 7;
    if (e < 9) {
      int ky = e / 3, kx = e % 3;
      int iy = 2 * y - 1 + ky, ix = 2 * x - 1 + kx;
      bool v = (iy >= 0 && iy < 14 && ix >= 0 && ix < 14);
      E.eh = v ? (W2F_OFF + e * 2048u) : ZOFF;
      E.el = v ? (E.eh + W2PL) : ZOFF;
      E.b = R1G + (iy * 14 + ix) * 26624;
      E.ars = 32; E.brs = 32;
    } else if (e < 27 && !post) {
      int u = e - 9, t = u >> 1, sub = u & 1, ky = t / 3, kx = t % 3;
      int ty = y + 1 - ky, tx = x + 1 - kx;
      bool v = (ty >= 0 && ty < 7 && tx >= 0 && tx < 7);
      E.eh = v ? (W3B_OFF + t * 4096u + sub * 32u) : ZOFF;
      E.el = v ? (E.eh + W3PL) : ZOFF;
      E.b = R3G + (ty * 7 + tx) * 53248 + sub * 32;
      E.ars = v ? 64 : 32; E.brs = 64;
    } else {
      E.eh = ZOFF; E.el = ZOFF; E.b = R4G; E.ars = 32; E.brs = 256;
    }
  } else {  // role 0: s1 update, conv2^T (parity taps)
    int y = p / 14, x = p % 14;
    int tj = e >> 1, sub = e & 1, jy = tj >> 1, jx = tj & 1;
    int ky = (y & 1) ? 2 * jy : 1;
    int kx = (x & 1) ? 2 * jx : 1;
    bool py_ = (y & 1) || (jy == 0);
    bool px_ = (x & 1) || (jx == 0);
    int oy = (y + 1 - ky) >> 1, ox = (x + 1 - kx) >> 1;
    bool v = py_ && px_ && oy >= 0 && oy < 7 && ox >= 0 && ox < 7;
    int t = ky * 3 + kx;
    E.eh = v ? (W2B_OFF + t * 2048u + sub * 32u) : ZOFF;
    E.el = v ? (E.eh + W2PL) : ZOFF;
    E.b = R2G + (oy * 7 + ox) * 53248 + sub * 32;
    E.ars = v ? 64 : 32; E.brs = 64;
  }
  return E;
}

// pipelined main loop: double-buffered LDS B-tiles (64n x 32k, 80B rows),
// stage(j+1) global->reg during MFMA(j), ds_write late, ONE barrier per chunk.
// APL: A planes (1 = iteration bf16, 2 = post hi/lo).
template <int APL, int MI, int NJ>
__device__ __forceinline__ void mloop(int role, int post, int p, int mt, int n0,
                                      int NC2, int mhalf, int nhalf,
                                      const ushort_t* __restrict__ S,
                                      const ushort_t* __restrict__ WP,
                                      ushort_t* __restrict__ SB,
                                      f4_t (&acc)[MI][NJ]) {
  const int tid = threadIdx.x, l = tid & 63;
  const int lm = l & 15, koff = (l >> 4) * 8;
  const int sn = tid >> 2, sc = (tid & 3) * 8;
  Ent E0 = entry(role, 0, p, mt, post);
  Ent E1 = entry(role, 1, p, mt, post);
  bf8_t s0 = *(const bf8_t*)(S + E0.b + (n0 + sn) * E0.brs + sc);
  bf8_t s1 = *(const bf8_t*)(S + E1.b + (n0 + sn) * E1.brs + sc);
  {
    int wb = sn * 40 + sc;
    *(bf8_t*)&SB[wb] = s0;
    *(bf8_t*)&SB[wb + 2560] = s1;
  }
  __syncthreads();
  for (int j = 0; j < NC2; ++j) {
    bf8_t a0[MI][APL], a1[MI][APL];
#pragma unroll
    for (int mi = 0; mi < MI; ++mi) {
      int mo0 = (mhalf + mi * 16 + lm) * E0.ars + koff;
      int mo1 = (mhalf + mi * 16 + lm) * E1.ars + koff;
      a0[mi][0] = *(const bf8_t*)(WP + E0.eh + mo0);
      a1[mi][0] = *(const bf8_t*)(WP + E1.eh + mo1);
      if (APL == 2) {
        a0[mi][APL - 1] = *(const bf8_t*)(WP + E0.el + mo0);
        a1[mi][APL - 1] = *(const bf8_t*)(WP + E1.el + mo1);
      }
    }
    bool more = (j + 1 < NC2);
    if (more) {
      E0 = entry(role, 2 * j + 2, p, mt, post);
      E1 = entry(role, 2 * j + 3, p, mt, post);
      s0 = *(const bf8_t*)(S + E0.b + (n0 + sn) * E0.brs + sc);
      s1 = *(const bf8_t*)(S + E1.b + (n0 + sn) * E1.brs + sc);
    }
    const ushort_t* Bb = SB + (j & 1) * 5120;
#pragma unroll
    for (int nj = 0; nj < NJ; ++nj) {
      int lo = (nhalf + nj * 16 + lm) * 40 + koff;
      bf8_t b0 = *(const bf8_t*)&Bb[lo];
      bf8_t b1 = *(const bf8_t*)&Bb[2560 + lo];
#pragma unroll
      for (int mi = 0; mi < MI; ++mi) {
#pragma unroll
        for (int pl = 0; pl < APL; ++pl) {
          acc[mi][nj] = MFMA16(a0[mi][pl], b0, acc[mi][nj], 0, 0, 0);
          acc[mi][nj] = MFMA16(a1[mi][pl], b1, acc[mi][nj], 0, 0, 0);
        }
      }
    }
    if (more) {
      ushort_t* Wb = SB + ((j + 1) & 1) * 5120;
      int wb = sn * 40 + sc;
      *(bf8_t*)&Wb[wb] = s0;
      *(bf8_t*)&Wb[wb + 2560] = s1;
    }
    __syncthreads();
  }
}

// mega kernel: blocks [role3 52][role2 637][role1 637][role0 2548 (iter only)]
template <int POST>
__global__ __launch_bounds__(256) void k_mega(
    const ushort_t* __restrict__ S, ushort_t* __restrict__ D,
    const ushort_t* __restrict__ G, const ushort_t* __restrict__ WP,
    const float* __restrict__ b2, const float* __restrict__ b3,
    const float* __restrict__ b4) {
  __shared__ __align__(16) ushort_t SB[10240];
  __shared__ float Lt[64 * 65];
  const int tid = threadIdx.x, l = tid & 63, w = tid >> 6;
  const int lm = l & 15, lk = l >> 4;
  int b = blockIdx.x;
  int role, rb;
  if (b < 52) { role = 3; rb = b; }
  else if (b < 689) { role = 2; rb = b - 52; }
  else if (b < 1326) { role = 1; rb = b - 689; }
  else { role = 0; rb = b - 1326; }

  int ntile = rb % 13, pq = rb / 13;
  int n0 = ntile * 64;

  if (role == 0) {
    f4_t acc[2][1] = {};
    mloop<1, 2, 1>(0, POST, pq, 0, n0, 4, 0, w * 16, S, WP, SB, acc);
#pragma unroll
    for (int mi = 0; mi < 2; ++mi)
#pragma unroll
      for (int r = 0; r < 4; ++r)
        Lt[(w * 16 + lm) * 33 + mi * 16 + lk * 4 + r] = acc[mi][0][r];
    __syncthreads();
    int nl = tid >> 2, cq = (tid & 3) * 8;
    int n = n0 + nl;
    size_t off = (size_t)R1G + (size_t)pq * 26624 + (size_t)n * 32 + cq;
    size_t goff = (size_t)pq * 26624 + (size_t)n * 32 + cq;
    bf8_t oh = *(const bf8_t*)&S[off];
    bf8_t gh = *(const bf8_t*)&G[goff], gl = *(const bf8_t*)&G[goff + GPL];
    const float* lp = Lt + nl * 33 + cq;
    bf8_t rh;
#pragma unroll
    for (int e = 0; e < 8; ++e) {
      float old = b2f((ushort_t)oh[e]);
      float u = bjoin((ushort_t)gh[e], (ushort_t)gl[e]);
      rh[e] = (short)bround(0.5f * old + 0.5f * (lp[e] + u));
    }
    *(bf8_t*)&D[off] = rh;
  } else {
    f4_t acc[2][2] = {};
    int NC2 = (role == 3) ? 49 : (role == 2) ? (POST ? 9 : 13) : (POST ? 5 : 14);
    mloop<POST + 1, 2, 2>(role, POST, pq, pq, n0, NC2, (w & 1) * 32, (w >> 1) * 32,
                          S, WP, SB, acc);
#pragma unroll
    for (int mi = 0; mi < 2; ++mi)
#pragma unroll
      for (int nj = 0; nj < 2; ++nj)
#pragma unroll
        for (int r = 0; r < 4; ++r)
          Lt[((w >> 1) * 32 + nj * 16 + lm) * 65 + (w & 1) * 32 + mi * 16 + lk * 4 + r] =
              acc[mi][nj][r];
    __syncthreads();
    int nl = tid >> 2, cq = (tid & 3) * 16;
    int n = n0 + nl;
    size_t off;
    const float* bias;
    int bq = cq;
    if (role == 1) { off = (size_t)R2G + (size_t)pq * 53248 + (size_t)n * 64 + cq; bias = b2; }
    else if (role == 2) { off = (size_t)R3G + (size_t)pq * 53248 + (size_t)n * 64 + cq; bias = b3; }
    else { off = (size_t)R4G + (size_t)n * 256 + pq * 64 + cq; bias = b4; bq = pq * 64 + cq; }
    const float* lp = Lt + nl * 65 + cq;
#pragma unroll
    for (int half = 0; half < 2; ++half) {
      size_t o8 = off + half * 8;
      bf8_t oh = *(const bf8_t*)&S[o8];
      bf8_t rh, rl;
#pragma unroll
      for (int e = 0; e < 8; ++e) {
        float v = lp[half * 8 + e];
        if (n == 784) v += bias[bq + half * 8 + e];
        float old = b2f((ushort_t)oh[e]);
        if (POST) {
          float nv = 0.5f * old - v;
          ushort_t h, l2; bsplit(nv, h, l2);
          rh[e] = (short)h; rl[e] = (short)l2;
        } else {
          rh[e] = (short)bround(0.5f * old + 0.5f * v);
        }
      }
      *(bf8_t*)&D[o8] = rh;
      if (POST) *(bf8_t*)&D[o8 + SELG] = rl;
    }
  }
}

// H-GEMM: HpT[z][n][j] = sum_d P[d][j] S[d][n] (partials), 128x128 tiles.
__device__ __forceinline__ void hstep(int s, size_t& base, int& C, int& c0) {
  if (s < 196) { base = R1G + (size_t)s * 26624; C = 32; c0 = 0; }
  else if (s < 294) { int u = s - 196; base = R2G + (size_t)(u >> 1) * 53248; C = 64; c0 = (u & 1) * 32; }
  else if (s < 392) { int u = s - 294; base = R3G + (size_t)(u >> 1) * 53248; C = 64; c0 = (u & 1) * 32; }
  else { base = R4G; C = 256; c0 = (s - 392) * 32; }
}

__global__ __launch_bounds__(256) void k_hgemm(float* __restrict__ HpT,
                                               const ushort_t* __restrict__ P,
                                               const ushort_t* __restrict__ S) {
  int tid = threadIdx.x, l = tid & 63, w = tid >> 6;
  int lm = l & 15, lk = l >> 4, koff = lk * 8;
  int m0 = blockIdx.y * 128 + (w & 1) * 64;
  int n0 = blockIdx.x * 128 + (w >> 1) * 64;
  int z = blockIdx.z;
  int s0 = (400 * z) / 7, s1e = (400 * (z + 1)) / 7;
  f4_t acc[4][4] = {};
  for (int s = s0; s < s1e; ++s) {
    size_t base; int C, c0;
    hstep(s, base, C, c0);
    const ushort_t* A = P + base + (size_t)(m0 + lm) * C + c0 + koff;
    const ushort_t* B = S + base + (size_t)(n0 + lm) * C + c0 + koff;
    bf8_t bfr[4];
#pragma unroll
    for (int nj = 0; nj < 4; ++nj) bfr[nj] = *(const bf8_t*)(B + (size_t)nj * 16 * C);
#pragma unroll
    for (int mi = 0; mi < 4; ++mi) {
      const ushort_t* Am = A + (size_t)mi * 16 * C;
      bf8_t ah = *(const bf8_t*)Am;
      bf8_t al = *(const bf8_t*)(Am + SELG);
#pragma unroll
      for (int nj = 0; nj < 4; ++nj) {
        acc[mi][nj] = MFMA16(ah, bfr[nj], acc[mi][nj], 0, 0, 0);
        acc[mi][nj] = MFMA16(al, bfr[nj], acc[mi][nj], 0, 0, 0);
      }
    }
  }
#pragma unroll
  for (int mi = 0; mi < 4; ++mi)
#pragma unroll
    for (int nj = 0; nj < 4; ++nj)
#pragma unroll
      for (int r = 0; r < 4; ++r) {
        int m = m0 + mi * 16 + lk * 4 + r;
        int n = n0 + nj * 16 + lm;
        if (m < NBn && n < NBn)
          HpT[((size_t)z * NBn + n) * NBn + m] = acc[mi][nj][r];
      }
}

// sum partials -> Ht hi/lo bf16 (Ht[n][j] = H[j][n])
__global__ void k_combT(ushort_t* __restrict__ HtH, ushort_t* __restrict__ HtL,
                        const float* __restrict__ HpT) {
  int idx = blockIdx.x * blockDim.x + threadIdx.x;
  if (idx >= NBn * NBn) return;
  float s = 0.f;
#pragma unroll
  for (int z = 0; z < 7; ++z) s += HpT[(size_t)z * NBn * NBn + idx];
  ushort_t h, l; bsplit(s, h, l);
  HtH[idx] = h; HtL[idx] = l;
}

// x~ hi/lo planes [Bn][832]: col 784 = 1.0 (affine), pads 0
__global__ void k_xsplit(ushort_t* __restrict__ XH, ushort_t* __restrict__ XL,
                         const float* __restrict__ x, int Bn) {
  int idx = blockIdx.x * blockDim.x + threadIdx.x;
  if (idx >= Bn * NBn) return;
  int i = idx / NBn, j = idx % NBn;
  float v = (j < 784) ? x[(size_t)i * 784 + j] : (j == 784 ? 1.f : 0.f);
  ushort_t h, l; bsplit(v, h, l);
  XH[idx] = h; XL[idx] = l;
}

// Y[i][n] = sum_j x~[i][j] H[j][n]  (MFMA hi/lo: xh*Hh + xh*Hl + xl*Hh)
__global__ __launch_bounds__(256) void k_ygemm(float* __restrict__ Y,
    const ushort_t* __restrict__ XH, const ushort_t* __restrict__ XL,
    const ushort_t* __restrict__ HtH, const ushort_t* __restrict__ HtL, int Bn) {
  int tid = threadIdx.x, l = tid & 63, w = tid >> 6;
  int lm = l & 15, lk = l >> 4, koff = lk * 8;
  int m0 = blockIdx.y * 64 + (w & 1) * 32;
  int n0 = blockIdx.x * 64 + (w >> 1) * 32;
  f4_t acc[2][2] = {};
  for (int k0 = 0; k0 < NBn; k0 += 32) {
    bf8_t bh[2], bl[2];
#pragma unroll
    for (int nj = 0; nj < 2; ++nj) {
      size_t bo = (size_t)(n0 + nj * 16 + lm) * NBn + k0 + koff;
      bh[nj] = *(const bf8_t*)(HtH + bo);
      bl[nj] = *(const bf8_t*)(HtL + bo);
    }
#pragma unroll
    for (int mi = 0; mi < 2; ++mi) {
      int mrow = m0 + mi * 16 + lm;
      if (mrow >= Bn) mrow = Bn - 1;
      size_t ao = (size_t)mrow * NBn + k0 + koff;
      bf8_t ah = *(const bf8_t*)(XH + ao);
      bf8_t al = *(const bf8_t*)(XL + ao);
#pragma unroll
      for (int nj = 0; nj < 2; ++nj) {
        acc[mi][nj] = MFMA16(ah, bh[nj], acc[mi][nj], 0, 0, 0);
        acc[mi][nj] = MFMA16(ah, bl[nj], acc[mi][nj], 0, 0, 0);
        acc[mi][nj] = MFMA16(al, bh[nj], acc[mi][nj], 0, 0, 0);
      }
    }
  }
#pragma unroll
  for (int mi = 0; mi < 2; ++mi)
#pragma unroll
    for (int nj = 0; nj < 2; ++nj)
#pragma unroll
      for (int r = 0; r < 4; ++r) {
        int m = m0 + mi * 16 + lk * 4 + r;
        int n = n0 + nj * 16 + lm;
        if (m < Bn) Y[(size_t)m * NBn + n] = acc[mi][nj][r];
      }
}

// out[i] = 0.5||x_i||^2 - vb.x_i + sum_{j<784} x_ij Y[i,j] + Y[i,784]
__global__ void k_out(float* __restrict__ out, const float* __restrict__ x,
                      const float* __restrict__ vb, const float* __restrict__ Y, int Bn) {
  int wave = threadIdx.x >> 6, lane = threadIdx.x & 63;
  int i = blockIdx.x * 4 + wave;
  if (i >= Bn) return;
  const float* xi = x + (size_t)i * 784;
  const float* yi = Y + (size_t)i * NBn;
  float s = 0.f;
  for (int j = lane; j < 784; j += 64) {
    float xv = xi[j];
    s += xv * (0.5f * xv - vb[j] + yi[j]);
  }
  for (int off = 32; off; off >>= 1) s += __shfl_down(s, off);
  if (lane == 0) out[i] = s + yi[784];
}

extern "C" void kernel_launch(void* const* d_in, const int* in_sizes, int n_in, void* d_out,
                              int out_size, void* d_ws, size_t ws_size, hipStream_t stream) {
  const float* x  = (const float*)d_in[0];
  const float* vb = (const float*)d_in[1];
  const float* w1 = (const float*)d_in[2];
  const float* b1 = (const float*)d_in[3];
  const float* w2 = (const float*)d_in[4];
  const float* b2 = (const float*)d_in[5];
  const float* w3 = (const float*)d_in[6];
  const float* b3 = (const float*)d_in[7];
  const float* w4 = (const float*)d_in[8];
  const float* b4 = (const float*)d_in[9];
  int Bn = in_sizes[0] / 784;
  float* out = (float*)d_out;

  ushort_t* S0 = (ushort_t*)d_ws;                    // SELG (single plane)
  ushort_t* S1 = S0 + (size_t)SELG;                  // SELG
  ushort_t* Pb = S1 + (size_t)SELG;                  // 2*SELG (hi/lo)
  ushort_t* G  = Pb + (size_t)2 * SELG;              // 2*GPL; reused as HpT after k_p1
  ushort_t* WP = G + (size_t)2 * GPL;                // WPTOT2
  ushort_t* HtH = WP + WPTOT2;                       // NBn*NBn
  ushort_t* HtL = HtH + (size_t)NBn * NBn;           // NBn*NBn
  float* HpT = (float*)G;                            // 7*NBn*NBn f32 (19.4MB <= 20.9MB)
  ushort_t* XH = Pb;                                 // Bn*NBn (Pb dead after hgemm)
  ushort_t* XL = XH + (size_t)Bn * NBn;
  float* Y = (float*)S1;                             // Bn*NBn f32 (S1 dead)

  const int TB = 256;
  k_fill0<<<2048, TB, 0, stream>>>((float*)S0, SELG / 2);
  k_fill0<<<2048, TB, 0, stream>>>((float*)S1, SELG / 2);
  k_fill0<<<2, TB, 0, stream>>>((float*)(WP + ZOFF), 1280);
  k_pack2<<<72, TB, 0, stream>>>(w2, WP);
  k_pack3<<<144, TB, 0, stream>>>(w3, WP);
  k_pack4<<<3136, TB, 0, stream>>>(w4, WP);
  k_u1b<<<20384, TB, 0, stream>>>(G, w1, b1);

  ushort_t* cur = S0;
  ushort_t* nxt = S1;
  for (int it = 0; it < NITER; ++it) {
    k_mega<0><<<3874, TB, 0, stream>>>(cur, nxt, G, WP, b2, b3, b4);
    ushort_t* t = cur; cur = nxt; nxt = t;
  }
  // cur == S0 (50 swaps even)

  // post fields P into Pb (hi/lo)
  k_p1<<<2548, TB, 0, stream>>>(Pb, cur, G);
  k_mega<1><<<1326, TB, 0, stream>>>(cur, Pb, G, WP, b2, b3, b4);

  // H partials (transposed) -> Ht hi/lo
  k_hgemm<<<dim3(7, 7, 7), TB, 0, stream>>>(HpT, Pb, cur);
  k_combT<<<(NBn * NBn + TB - 1) / TB, TB, 0, stream>>>(HtH, HtL, HpT);

  // Y = x~ * H via MFMA, then out
  k_xsplit<<<(Bn * NBn + TB - 1) / TB, TB, 0, stream>>>(XH, XL, x, Bn);
  k_ygemm<<<dim3(13, (Bn + 63) / 64), TB, 0, stream>>>(Y, XH, XL, HtH, HtL, Bn);
  k_out<<<(Bn + 3) / 4, TB, 0, stream>>>(out, x, vb, Y, Bn);
}